// Round 2
// baseline (1478.854 us; speedup 1.0000x reference)
//
#include <hip/hip_runtime.h>

#define FIN 128
#define H1_ 50
#define H2_ 10

// ---------------- degree / norm ----------------

__global__ void init_deg(float* __restrict__ deg, int n) {
    int i = blockIdx.x * blockDim.x + threadIdx.x;
    if (i < n) deg[i] = 1.0f;   // self-loop contributes 1 to every node's in-degree
}

__global__ void deg_count(const int* __restrict__ dst, float* __restrict__ deg, int E) {
    int i = blockIdx.x * blockDim.x + threadIdx.x;
    if (i < E) atomicAdd(&deg[dst[i]], 1.0f);
}

__global__ void deg_to_dinv(float* __restrict__ deg, int n) {
    int i = blockIdx.x * blockDim.x + threadIdx.x;
    if (i < n) deg[i] = 1.0f / sqrtf(deg[i]);   // deg >= 1 always (self-loops)
}

// ---------------- GEMM1: tmp1[N,50] = x[N,128] @ W1[128,50] ----------------

#define G1_NODES 16
__global__ __launch_bounds__(256) void gemm1_kernel(const float* __restrict__ x,
                                                    const float* __restrict__ W1,
                                                    float* __restrict__ tmp1, int N) {
    __shared__ float sW[FIN * H1_];        // 25.6 KB, layout [k][f]
    __shared__ float sX[G1_NODES * FIN];   // 8 KB
    int tid = threadIdx.x;
    for (int i = tid; i < FIN * H1_; i += 256) sW[i] = W1[i];
    int nb = blockIdx.x * G1_NODES;
    for (int i = tid; i < G1_NODES * FIN; i += 256) {
        int ln = i >> 7;                   // i / 128
        sX[i] = (nb + ln < N) ? x[(size_t)nb * FIN + i] : 0.0f;
    }
    __syncthreads();
    for (int oi = tid; oi < G1_NODES * H1_; oi += 256) {
        int ln = oi / H1_;
        int f  = oi - ln * H1_;
        if (nb + ln >= N) continue;
        const float* xr = &sX[ln * FIN];
        float acc = 0.0f;
#pragma unroll 16
        for (int k = 0; k < FIN; ++k) acc = fmaf(xr[k], sW[k * H1_ + f], acc);
        tmp1[(size_t)nb * H1_ + oi] = acc;   // oi == ln*50+f, contiguous
    }
}

// ---------------- edge aggregation (atomic scatter) ----------------

template <int F>
__global__ void aggregate(const float* __restrict__ tmp, const int* __restrict__ src,
                          const int* __restrict__ dst, const float* __restrict__ dinv,
                          float* __restrict__ out, int E) {
    int idx = blockIdx.x * blockDim.x + threadIdx.x;
    if (idx >= E * F) return;
    int e = idx / F;               // compiler magic-div (F constant)
    int f = idx - e * F;
    int s = src[e];
    int d = dst[e];
    float v = tmp[s * F + f] * (dinv[s] * dinv[d]);
    atomicAdd(&out[d * F + f], v);
}

// ---------------- self-loop + bias (+relu) epilogue, in place ----------------

template <int F, bool RELU>
__global__ void self_bias(const float* __restrict__ tmp, const float* __restrict__ dinv,
                          const float* __restrict__ b, float* __restrict__ out, int n) {
    int idx = blockIdx.x * blockDim.x + threadIdx.x;
    if (idx >= n) return;
    int node = idx / F;
    int f    = idx - node * F;
    float di = dinv[node];
    float v  = out[idx] + tmp[idx] * di * di + b[f];
    out[idx] = RELU ? fmaxf(v, 0.0f) : v;
}

// ---------------- GEMM2: tmp2[N,10] = h[N,50] @ W2[50,10] ----------------

__global__ __launch_bounds__(256) void gemm2_kernel(const float* __restrict__ h,
                                                    const float* __restrict__ W2,
                                                    float* __restrict__ tmp2, int n) {
    __shared__ float sW[H1_ * H2_];   // 2 KB
    int tid = threadIdx.x;
    for (int i = tid; i < H1_ * H2_; i += 256) sW[i] = W2[i];
    __syncthreads();
    int idx = blockIdx.x * blockDim.x + tid;
    if (idx >= n) return;
    int node = idx / H2_;
    int f    = idx - node * H2_;
    const float* hr = &h[node * H1_];
    float acc = 0.0f;
#pragma unroll
    for (int k = 0; k < H1_; ++k) acc = fmaf(hr[k], sW[k * H2_ + f], acc);
    tmp2[idx] = acc;
}

// ---------------- decode: logits[i] = dot(z[a], z[b]) over 10 dims ----------------

__global__ void decode_kernel(const float* __restrict__ z, const int* __restrict__ pos,
                              const int* __restrict__ neg, float* __restrict__ logits, int EP) {
    int i = blockIdx.x * blockDim.x + threadIdx.x;
    if (i >= 2 * EP) return;
    int a, b;
    if (i < EP) { a = pos[i]; b = pos[EP + i]; }
    else        { int j = i - EP; a = neg[j]; b = neg[EP + j]; }
    const float* za = &z[a * H2_];
    const float* zb = &z[b * H2_];
    float acc = 0.0f;
#pragma unroll
    for (int f = 0; f < H2_; ++f) acc = fmaf(za[f], zb[f], acc);
    logits[i] = acc;
}

// ---------------- launch ----------------

extern "C" void kernel_launch(void* const* d_in, const int* in_sizes, int n_in,
                              void* d_out, int out_size, void* d_ws, size_t ws_size,
                              hipStream_t stream) {
    const float* x   = (const float*)d_in[0];
    const float* W1  = (const float*)d_in[1];
    const float* b1  = (const float*)d_in[2];
    const float* W2  = (const float*)d_in[3];
    const float* b2  = (const float*)d_in[4];
    const int* train = (const int*)d_in[5];
    const int* pos   = (const int*)d_in[6];
    const int* neg   = (const int*)d_in[7];

    const int N  = in_sizes[0] / FIN;       // 100000
    const int E  = in_sizes[5] / 2;         // 3200000
    const int EP = in_sizes[6] / 2;         // 1600000

    const int* tsrc = train;
    const int* tdst = train + E;

    // workspace layout (floats), peak 101N = 40.4 MB:
    //   deg[N] | region A: tmp1[N*50] (later overlaid by tmp2[N*10] + out2[N*10])
    //          | region B: out1[N*50] (h in place)
    float* ws   = (float*)d_ws;
    float* deg  = ws;
    float* tmp1 = deg  + N;
    float* out1 = tmp1 + (size_t)N * H1_;     // h (post-relu) in place
    float* tmp2 = tmp1;                        // overlays tmp1 (dead after conv1 epilogue)
    float* out2 = tmp1 + (size_t)N * H2_;      // z, overlays tmp1[N*10 .. N*20)
    float* logits = (float*)d_out;

    // zero conv1 scatter target (ws is poisoned 0xAA)
    hipMemsetAsync(out1, 0, (size_t)N * H1_ * sizeof(float), stream);

    init_deg<<<(N + 255) / 256, 256, 0, stream>>>(deg, N);
    deg_count<<<(E + 255) / 256, 256, 0, stream>>>(tdst, deg, E);
    deg_to_dinv<<<(N + 255) / 256, 256, 0, stream>>>(deg, N);

    gemm1_kernel<<<(N + G1_NODES - 1) / G1_NODES, 256, 0, stream>>>(x, W1, tmp1, N);

    int tot1 = E * H1_;   // 160M, fits int32
    aggregate<H1_><<<(tot1 + 255) / 256, 256, 0, stream>>>(tmp1, tsrc, tdst, deg, out1, E);
    self_bias<H1_, true><<<(N * H1_ + 255) / 256, 256, 0, stream>>>(tmp1, deg, b1, out1, N * H1_);

    // tmp1 region now dead; reuse for tmp2/out2
    gemm2_kernel<<<(N * H2_ + 255) / 256, 256, 0, stream>>>(out1, W2, tmp2, N * H2_);

    // zero conv2 scatter target
    hipMemsetAsync(out2, 0, (size_t)N * H2_ * sizeof(float), stream);

    int tot2 = E * H2_;   // 32M
    aggregate<H2_><<<(tot2 + 255) / 256, 256, 0, stream>>>(tmp2, tsrc, tdst, deg, out2, E);
    self_bias<H2_, false><<<(N * H2_ + 255) / 256, 256, 0, stream>>>(tmp2, deg, b2, out2, N * H2_);

    decode_kernel<<<(2 * EP + 255) / 256, 256, 0, stream>>>(out2, pos, neg, logits, EP);
}

// Round 3
// 852.918 us; speedup vs baseline: 1.7339x; 1.7339x over previous
//
#include <hip/hip_runtime.h>

#define FIN 128
#define H1_ 50
#define H2_ 10

// ================= CSR build =================

__global__ void hist_kernel(const int* __restrict__ dst, int* __restrict__ cnt, int E) {
    int e = blockIdx.x * blockDim.x + threadIdx.x;
    if (e < E) atomicAdd(&cnt[dst[e]], 1);
}

// block scans 1024 counts (4/thread), writes exclusive-in-block prefix to rowptr,
// block total to partials[blockIdx]
__global__ __launch_bounds__(256) void scan_block(const int* __restrict__ cnt,
                                                  int* __restrict__ rowptr,
                                                  int* __restrict__ partials, int N) {
    __shared__ int sSum[256];
    int t = threadIdx.x;
    int base = blockIdx.x * 1024 + t * 4;
    int v0 = (base + 0 < N) ? cnt[base + 0] : 0;
    int v1 = (base + 1 < N) ? cnt[base + 1] : 0;
    int v2 = (base + 2 < N) ? cnt[base + 2] : 0;
    int v3 = (base + 3 < N) ? cnt[base + 3] : 0;
    int tsum = v0 + v1 + v2 + v3;
    sSum[t] = tsum;
    __syncthreads();
    for (int off = 1; off < 256; off <<= 1) {
        int x = (t >= off) ? sSum[t - off] : 0;
        __syncthreads();
        sSum[t] += x;
        __syncthreads();
    }
    int excl = sSum[t] - tsum;
    if (t == 255) partials[blockIdx.x] = sSum[255];
    if (base + 0 < N) rowptr[base + 0] = excl;
    excl += v0;
    if (base + 1 < N) rowptr[base + 1] = excl;
    excl += v1;
    if (base + 2 < N) rowptr[base + 2] = excl;
    excl += v2;
    if (base + 3 < N) rowptr[base + 3] = excl;
}

// single block: exclusive-scan up to 128 block partials in place
__global__ void scan_partials(int* __restrict__ partials, int nb) {
    __shared__ int s[128];
    int t = threadIdx.x;
    int v = (t < nb) ? partials[t] : 0;
    s[t] = v;
    __syncthreads();
    for (int off = 1; off < 128; off <<= 1) {
        int x = (t >= off) ? s[t - off] : 0;
        __syncthreads();
        s[t] += x;
        __syncthreads();
    }
    if (t < nb) partials[t] = s[t] - v;
}

// rowptr += scanned partial; dinv = rsqrt(1+deg); cursor (aliases cnt) = rowptr
__global__ void finalize_kernel(int* __restrict__ cnt_cursor, int* __restrict__ rowptr,
                                const int* __restrict__ partials, float* __restrict__ dinv,
                                int N, int E) {
    int i = blockIdx.x * blockDim.x + threadIdx.x;
    if (i == 0) rowptr[N] = E;
    if (i >= N) return;
    int c = cnt_cursor[i];
    dinv[i] = rsqrtf(1.0f + (float)c);     // deg includes self-loop
    int rp = rowptr[i] + partials[i >> 10];
    rowptr[i] = rp;
    cnt_cursor[i] = rp;                    // becomes write cursor
}

__global__ void fill_csr(const int* __restrict__ src, const int* __restrict__ dst,
                         int* __restrict__ cursor, int* __restrict__ ecol, int E) {
    int e = blockIdx.x * blockDim.x + threadIdx.x;
    if (e >= E) return;
    int d = dst[e];
    int pos = atomicAdd(&cursor[d], 1);
    ecol[pos] = src[e];
}

// ================= GEMM1: st1[N,50] = (x @ W1) * dinv[node] =================

#define G1_NODES 16
__global__ __launch_bounds__(256) void gemm1_kernel(const float* __restrict__ x,
                                                    const float* __restrict__ W1,
                                                    const float* __restrict__ dinv,
                                                    float* __restrict__ st1, int N) {
    __shared__ float sW[FIN * H1_];        // [k][f], 25.6 KB
    __shared__ float sX[G1_NODES * FIN];   // 8 KB
    int tid = threadIdx.x;
    {   // vectorized stages (N % 16 == 0, FIN*H1 % 4 == 0)
        const float4* W4 = (const float4*)W1;
        float4* sW4 = (float4*)sW;
        for (int i = tid; i < FIN * H1_ / 4; i += 256) sW4[i] = W4[i];
        const float4* x4 = (const float4*)(x + (size_t)blockIdx.x * G1_NODES * FIN);
        float4* sX4 = (float4*)sX;
        for (int i = tid; i < G1_NODES * FIN / 4; i += 256) sX4[i] = x4[i];
    }
    __syncthreads();
    int nb = blockIdx.x * G1_NODES;
    for (int oi = tid; oi < G1_NODES * H1_; oi += 256) {
        int ln = oi / H1_;
        int f  = oi - ln * H1_;
        const float* xr = &sX[ln * FIN];
        float acc = 0.0f;
#pragma unroll 16
        for (int k = 0; k < FIN; ++k) acc = fmaf(xr[k], sW[k * H1_ + f], acc);
        st1[(size_t)nb * H1_ + oi] = acc * dinv[nb + ln];
    }
}

// ================= GEMM2: st2[N,10] = (h @ W2) * dinv[node] =================

__global__ __launch_bounds__(256) void gemm2_kernel(const float* __restrict__ h,
                                                    const float* __restrict__ W2,
                                                    const float* __restrict__ dinv,
                                                    float* __restrict__ st2, int n) {
    __shared__ float sW[H1_ * H2_];   // 2 KB
    int tid = threadIdx.x;
    for (int i = tid; i < H1_ * H2_; i += 256) sW[i] = W2[i];
    __syncthreads();
    int idx = blockIdx.x * blockDim.x + tid;
    if (idx >= n) return;
    int node = idx / H2_;
    int f    = idx - node * H2_;
    const float* hr = &h[node * H1_];
    float acc = 0.0f;
#pragma unroll
    for (int k = 0; k < H1_; ++k) acc = fmaf(hr[k], sW[k * H2_ + f], acc);
    st2[idx] = acc * dinv[node];
}

// ================= CSR gather aggregation (fused self-loop + bias [+relu]) ====
// out[d,f] = (relu?)( dinv[d] * ( st[d,f] + sum_{s in nbr(d)} st[s,f] ) + b[f] )

template <int F, bool RELU>
__global__ __launch_bounds__(256) void csr_aggregate(const float* __restrict__ st,
                                                     const int* __restrict__ rowptr,
                                                     const int* __restrict__ ecol,
                                                     const float* __restrict__ dinv,
                                                     const float* __restrict__ b,
                                                     float* __restrict__ out, int N) {
    int idx = blockIdx.x * blockDim.x + threadIdx.x;
    if (idx >= N * F) return;
    int d = idx / F;
    int f = idx - d * F;
    float acc = st[idx];            // self-loop term
    int j = rowptr[d], end = rowptr[d + 1];
    for (; j + 3 < end; j += 4) {
        int s0 = ecol[j], s1 = ecol[j + 1], s2 = ecol[j + 2], s3 = ecol[j + 3];
        float a0 = st[s0 * F + f], a1 = st[s1 * F + f];
        float a2 = st[s2 * F + f], a3 = st[s3 * F + f];
        acc += (a0 + a1) + (a2 + a3);
    }
    for (; j < end; ++j) acc += st[ecol[j] * F + f];
    float v = fmaf(dinv[d], acc, b[f]);
    out[idx] = RELU ? fmaxf(v, 0.0f) : v;
}

// ================= decode =================

__global__ void decode_kernel(const float* __restrict__ z, const int* __restrict__ pos,
                              const int* __restrict__ neg, float* __restrict__ logits, int EP) {
    int i = blockIdx.x * blockDim.x + threadIdx.x;
    if (i >= 2 * EP) return;
    int a, b;
    if (i < EP) { a = pos[i]; b = pos[EP + i]; }
    else        { int j = i - EP; a = neg[j]; b = neg[EP + j]; }
    const float* za = &z[a * H2_];
    const float* zb = &z[b * H2_];
    float acc = 0.0f;
#pragma unroll
    for (int f = 0; f < H2_; ++f) acc = fmaf(za[f], zb[f], acc);
    logits[i] = acc;
}

// ================= launch =================

extern "C" void kernel_launch(void* const* d_in, const int* in_sizes, int n_in,
                              void* d_out, int out_size, void* d_ws, size_t ws_size,
                              hipStream_t stream) {
    const float* x   = (const float*)d_in[0];
    const float* W1  = (const float*)d_in[1];
    const float* b1  = (const float*)d_in[2];
    const float* W2  = (const float*)d_in[3];
    const float* b2  = (const float*)d_in[4];
    const int* train = (const int*)d_in[5];
    const int* pos   = (const int*)d_in[6];
    const int* neg   = (const int*)d_in[7];

    const int N  = in_sizes[0] / FIN;       // 100000
    const int E  = in_sizes[5] / 2;         // 3200000
    const int EP = in_sizes[6] / 2;         // 1600000

    const int* tsrc = train;
    const int* tdst = train + E;

    // ---- workspace layout (~41.6 MB peak) ----
    // ints: cnt/cursor[N] | rowptr[N+1] | partials[128]
    // floats: dinv[N] | st1[50N] (st2 overlays [0,10N), out2 overlays [10N,20N)) | out1[50N]
    int* cnt      = (int*)d_ws;          // aliases cursor after finalize
    int* rowptr   = cnt + N;
    int* partials = rowptr + N + 1;
    float* dinv   = (float*)(partials + 128);
    float* st1    = dinv + N;
    float* out1   = st1 + (size_t)50 * N;    // h after relu
    float* st2    = st1;                      // overlays st1 (dead after agg1)
    float* out2   = st1 + (size_t)10 * N;     // z
    int* ecol     = (int*)d_out;              // E ints == out_size floats; dead before decode
    float* logits = (float*)d_out;

    // ---- CSR build ----
    hipMemsetAsync(cnt, 0, (size_t)N * sizeof(int), stream);
    hist_kernel<<<(E + 255) / 256, 256, 0, stream>>>(tdst, cnt, E);
    int nb = (N + 1023) / 1024;               // 98 <= 128
    scan_block<<<nb, 256, 0, stream>>>(cnt, rowptr, partials, N);
    scan_partials<<<1, 128, 0, stream>>>(partials, nb);
    finalize_kernel<<<(N + 255) / 256, 256, 0, stream>>>(cnt, rowptr, partials, dinv, N, E);
    fill_csr<<<(E + 255) / 256, 256, 0, stream>>>(tsrc, tdst, cnt, ecol, E);

    // ---- layer 1 ----
    gemm1_kernel<<<(N + G1_NODES - 1) / G1_NODES, 256, 0, stream>>>(x, W1, dinv, st1, N);
    csr_aggregate<H1_, true><<<(N * H1_ + 255) / 256, 256, 0, stream>>>(
        st1, rowptr, ecol, dinv, b1, out1, N);

    // ---- layer 2 ----
    gemm2_kernel<<<(N * H2_ + 255) / 256, 256, 0, stream>>>(out1, W2, dinv, st2, N * H2_);
    csr_aggregate<H2_, false><<<(N * H2_ + 255) / 256, 256, 0, stream>>>(
        st2, rowptr, ecol, dinv, b2, out2, N);

    // ---- decode ----
    decode_kernel<<<(2 * EP + 255) / 256, 256, 0, stream>>>(out2, pos, neg, logits, EP);
}

// Round 4
// 687.562 us; speedup vs baseline: 2.1509x; 1.2405x over previous
//
#include <hip/hip_runtime.h>

#define FIN 128
#define H1_ 50
#define H2_ 10

#define BKT_SHIFT 7
#define BKT_W 128              // nodes per bucket
#define NB_MAX 800             // >= ceil(100000/128) = 782
#define P1_CHUNK 8192          // edges per block in partition pass

// ================= CSR build: hist + scan =================

__global__ void hist_kernel(const int* __restrict__ dst, int* __restrict__ cnt, int E) {
    int e = blockIdx.x * blockDim.x + threadIdx.x;
    if (e < E) atomicAdd(&cnt[dst[e]], 1);
}

// block scans 1024 counts (4/thread) -> exclusive-in-block prefix + block total
__global__ __launch_bounds__(256) void scan_block(const int* __restrict__ cnt,
                                                  int* __restrict__ rowptr,
                                                  int* __restrict__ partials, int N) {
    __shared__ int sSum[256];
    int t = threadIdx.x;
    int base = blockIdx.x * 1024 + t * 4;
    int v0 = (base + 0 < N) ? cnt[base + 0] : 0;
    int v1 = (base + 1 < N) ? cnt[base + 1] : 0;
    int v2 = (base + 2 < N) ? cnt[base + 2] : 0;
    int v3 = (base + 3 < N) ? cnt[base + 3] : 0;
    int tsum = v0 + v1 + v2 + v3;
    sSum[t] = tsum;
    __syncthreads();
    for (int off = 1; off < 256; off <<= 1) {
        int x = (t >= off) ? sSum[t - off] : 0;
        __syncthreads();
        sSum[t] += x;
        __syncthreads();
    }
    int excl = sSum[t] - tsum;
    if (t == 255) partials[blockIdx.x] = sSum[255];
    if (base + 0 < N) rowptr[base + 0] = excl;
    excl += v0;
    if (base + 1 < N) rowptr[base + 1] = excl;
    excl += v1;
    if (base + 2 < N) rowptr[base + 2] = excl;
    excl += v2;
    if (base + 3 < N) rowptr[base + 3] = excl;
}

__global__ void scan_partials(int* __restrict__ partials, int nb) {
    __shared__ int s[128];
    int t = threadIdx.x;
    int v = (t < nb) ? partials[t] : 0;
    s[t] = v;
    __syncthreads();
    for (int off = 1; off < 128; off <<= 1) {
        int x = (t >= off) ? s[t - off] : 0;
        __syncthreads();
        s[t] += x;
        __syncthreads();
    }
    if (t < nb) partials[t] = s[t] - v;
}

// rowptr += scanned partial; dinv = rsqrt(1+deg); rowptr[N] = E
__global__ void finalize_kernel(const int* __restrict__ cnt, int* __restrict__ rowptr,
                                const int* __restrict__ partials, float* __restrict__ dinv,
                                int N, int E) {
    int i = blockIdx.x * blockDim.x + threadIdx.x;
    if (i == 0) rowptr[N] = E;
    if (i >= N) return;
    dinv[i] = rsqrtf(1.0f + (float)cnt[i]);     // deg includes self-loop
    rowptr[i] += partials[i >> 10];
}

// bucket cursors: bucket b's pairbuf segment starts at rowptr[b*128]
__global__ void init_bcursor(const int* __restrict__ rowptr, int* __restrict__ bcursor, int nb2) {
    int b = blockIdx.x * blockDim.x + threadIdx.x;
    if (b < nb2) bcursor[b] = rowptr[b << BKT_SHIFT];
}

// ================= pass 1: partition edges into 128-node buckets =================
// each block: LDS histogram over buckets -> reserve global ranges -> grouped write

__global__ __launch_bounds__(256) void partition_pass1(const int* __restrict__ src,
                                                       const int* __restrict__ dst,
                                                       int* __restrict__ bcursor,
                                                       int2* __restrict__ pairbuf, int E) {
    __shared__ int lhist[NB_MAX];
    __shared__ int lbase[NB_MAX];
    int tid = threadIdx.x;
    for (int i = tid; i < NB_MAX; i += 256) lhist[i] = 0;
    __syncthreads();
    int lo = blockIdx.x * P1_CHUNK;
    int hi = min(lo + P1_CHUNK, E);
    for (int e = lo + tid; e < hi; e += 256)
        atomicAdd(&lhist[dst[e] >> BKT_SHIFT], 1);
    __syncthreads();
    for (int b = tid; b < NB_MAX; b += 256) {
        int c = lhist[b];
        lbase[b] = c ? atomicAdd(&bcursor[b], c) : 0;
    }
    __syncthreads();
    for (int i = tid; i < NB_MAX; i += 256) lhist[i] = 0;   // reuse as local cursor
    __syncthreads();
    for (int e = lo + tid; e < hi; e += 256) {
        int s = src[e], d = dst[e];
        int b = d >> BKT_SHIFT;
        int r = atomicAdd(&lhist[b], 1);
        pairbuf[lbase[b] + r] = make_int2(s, d);
    }
}

// ================= pass 2: within-bucket fill (single-writer dense lines) ======

__global__ __launch_bounds__(256) void bucket_fill(const int2* __restrict__ pairbuf,
                                                   const int* __restrict__ rowptr,
                                                   int* __restrict__ ecol, int N) {
    __shared__ int cur[BKT_W];
    int b = blockIdx.x;
    int base_node = b << BKT_SHIFT;
    int nnodes = min(BKT_W, N - base_node);
    int tid = threadIdx.x;
    if (tid < nnodes) cur[tid] = rowptr[base_node + tid];
    __syncthreads();
    int start = rowptr[base_node];
    int endp  = rowptr[min(base_node + BKT_W, N)];
    for (int j = start + tid; j < endp; j += 256) {
        int2 p = pairbuf[j];
        int pos = atomicAdd(&cur[p.y - base_node], 1);
        ecol[pos] = p.x;
    }
}

// ================= GEMM1: st1[N,50] = (x @ W1) * dinv[node] =================

#define G1_NODES 16
__global__ __launch_bounds__(256) void gemm1_kernel(const float* __restrict__ x,
                                                    const float* __restrict__ W1,
                                                    const float* __restrict__ dinv,
                                                    float* __restrict__ st1, int N) {
    __shared__ float sW[FIN * H1_];        // [k][f], 25.6 KB
    __shared__ float sX[G1_NODES * FIN];   // 8 KB
    int tid = threadIdx.x;
    {
        const float4* W4 = (const float4*)W1;
        float4* sW4 = (float4*)sW;
        for (int i = tid; i < FIN * H1_ / 4; i += 256) sW4[i] = W4[i];
        const float4* x4 = (const float4*)(x + (size_t)blockIdx.x * G1_NODES * FIN);
        float4* sX4 = (float4*)sX;
        for (int i = tid; i < G1_NODES * FIN / 4; i += 256) sX4[i] = x4[i];
    }
    __syncthreads();
    int nb = blockIdx.x * G1_NODES;
    for (int oi = tid; oi < G1_NODES * H1_; oi += 256) {
        int ln = oi / H1_;
        int f  = oi - ln * H1_;
        const float* xr = &sX[ln * FIN];
        float acc = 0.0f;
#pragma unroll 16
        for (int k = 0; k < FIN; ++k) acc = fmaf(xr[k], sW[k * H1_ + f], acc);
        st1[(size_t)nb * H1_ + oi] = acc * dinv[nb + ln];
    }
}

// ================= GEMM2: st2[N,10] = (h @ W2) * dinv[node] =================

__global__ __launch_bounds__(256) void gemm2_kernel(const float* __restrict__ h,
                                                    const float* __restrict__ W2,
                                                    const float* __restrict__ dinv,
                                                    float* __restrict__ st2, int n) {
    __shared__ float sW[H1_ * H2_];   // 2 KB
    int tid = threadIdx.x;
    for (int i = tid; i < H1_ * H2_; i += 256) sW[i] = W2[i];
    __syncthreads();
    int idx = blockIdx.x * blockDim.x + tid;
    if (idx >= n) return;
    int node = idx / H2_;
    int f    = idx - node * H2_;
    const float* hr = &h[node * H1_];
    float acc = 0.0f;
#pragma unroll
    for (int k = 0; k < H1_; ++k) acc = fmaf(hr[k], sW[k * H2_ + f], acc);
    st2[idx] = acc * dinv[node];
}

// ================= CSR gather aggregation (fused self-loop + bias [+relu]) ====

template <int F, bool RELU>
__global__ __launch_bounds__(256) void csr_aggregate(const float* __restrict__ st,
                                                     const int* __restrict__ rowptr,
                                                     const int* __restrict__ ecol,
                                                     const float* __restrict__ dinv,
                                                     const float* __restrict__ b,
                                                     float* __restrict__ out, int N) {
    int idx = blockIdx.x * blockDim.x + threadIdx.x;
    if (idx >= N * F) return;
    int d = idx / F;
    int f = idx - d * F;
    float acc = st[idx];            // self-loop term
    int j = rowptr[d], end = rowptr[d + 1];
    for (; j + 3 < end; j += 4) {
        int s0 = ecol[j], s1 = ecol[j + 1], s2 = ecol[j + 2], s3 = ecol[j + 3];
        float a0 = st[s0 * F + f], a1 = st[s1 * F + f];
        float a2 = st[s2 * F + f], a3 = st[s3 * F + f];
        acc += (a0 + a1) + (a2 + a3);
    }
    for (; j < end; ++j) acc += st[ecol[j] * F + f];
    float v = fmaf(dinv[d], acc, b[f]);
    out[idx] = RELU ? fmaxf(v, 0.0f) : v;
}

// ================= decode =================

__global__ void decode_kernel(const float* __restrict__ z, const int* __restrict__ pos,
                              const int* __restrict__ neg, float* __restrict__ logits, int EP) {
    int i = blockIdx.x * blockDim.x + threadIdx.x;
    if (i >= 2 * EP) return;
    int a, b;
    if (i < EP) { a = pos[i]; b = pos[EP + i]; }
    else        { int j = i - EP; a = neg[j]; b = neg[EP + j]; }
    const float* za = &z[a * H2_];
    const float* zb = &z[b * H2_];
    float acc = 0.0f;
#pragma unroll
    for (int f = 0; f < H2_; ++f) acc = fmaf(za[f], zb[f], acc);
    logits[i] = acc;
}

// ================= launch =================

extern "C" void kernel_launch(void* const* d_in, const int* in_sizes, int n_in,
                              void* d_out, int out_size, void* d_ws, size_t ws_size,
                              hipStream_t stream) {
    const float* x   = (const float*)d_in[0];
    const float* W1  = (const float*)d_in[1];
    const float* b1  = (const float*)d_in[2];
    const float* W2  = (const float*)d_in[3];
    const float* b2  = (const float*)d_in[4];
    const int* train = (const int*)d_in[5];
    const int* pos   = (const int*)d_in[6];
    const int* neg   = (const int*)d_in[7];

    const int N  = in_sizes[0] / FIN;       // 100000
    const int E  = in_sizes[5] / 2;         // 3200000
    const int EP = in_sizes[6] / 2;         // 1600000

    const int* tsrc = train;
    const int* tdst = train + E;

    // ---- workspace layout (~41.2 MB peak) ----
    // ints: cnt[N] | rowptr[N+2] | partials[128] | bcursor[1024]
    // floats: dinv[N] | big region: union{ pairbuf int2[E]=25.6MB ; st1[50N]+out1[50N]=40MB }
    size_t off = 0;
    int* cnt      = (int*)d_ws;              off += N;
    int* rowptr   = (int*)d_ws + off;        off += (size_t)N + 2;
    int* partials = (int*)d_ws + off;        off += 128;
    int* bcursor  = (int*)d_ws + off;        off += 1024;
    float* dinv   = (float*)d_ws + off;      off += N;
    off = (off + 3) & ~(size_t)3;            // 16B-align big region
    float* big    = (float*)d_ws + off;
    int2* pairbuf = (int2*)big;              // dead before gemm1
    float* st1    = big;
    float* out1   = st1 + (size_t)50 * N;    // h after relu
    float* st2    = st1;                      // overlays st1 (dead after agg1)
    float* out2   = st1 + (size_t)10 * N;     // z
    int* ecol     = (int*)d_out;              // E ints; dead before decode overwrites
    float* logits = (float*)d_out;

    const int NB2 = (N + BKT_W - 1) >> BKT_SHIFT;   // 782 <= NB_MAX

    // ---- CSR build ----
    hipMemsetAsync(cnt, 0, (size_t)N * sizeof(int), stream);
    hist_kernel<<<(E + 255) / 256, 256, 0, stream>>>(tdst, cnt, E);
    int nb = (N + 1023) / 1024;               // 98 <= 128
    scan_block<<<nb, 256, 0, stream>>>(cnt, rowptr, partials, N);
    scan_partials<<<1, 128, 0, stream>>>(partials, nb);
    finalize_kernel<<<(N + 255) / 256, 256, 0, stream>>>(cnt, rowptr, partials, dinv, N, E);
    init_bcursor<<<(NB2 + 255) / 256, 256, 0, stream>>>(rowptr, bcursor, NB2);
    partition_pass1<<<(E + P1_CHUNK - 1) / P1_CHUNK, 256, 0, stream>>>(tsrc, tdst, bcursor, pairbuf, E);
    bucket_fill<<<NB2, 256, 0, stream>>>(pairbuf, rowptr, ecol, N);

    // ---- layer 1 ----
    gemm1_kernel<<<(N + G1_NODES - 1) / G1_NODES, 256, 0, stream>>>(x, W1, dinv, st1, N);
    csr_aggregate<H1_, true><<<(N * H1_ + 255) / 256, 256, 0, stream>>>(
        st1, rowptr, ecol, dinv, b1, out1, N);

    // ---- layer 2 ----
    gemm2_kernel<<<(N * H2_ + 255) / 256, 256, 0, stream>>>(out1, W2, dinv, st2, N * H2_);
    csr_aggregate<H2_, false><<<(N * H2_ + 255) / 256, 256, 0, stream>>>(
        st2, rowptr, ecol, dinv, b2, out2, N);

    // ---- decode ----
    decode_kernel<<<(2 * EP + 255) / 256, 256, 0, stream>>>(out2, pos, neg, logits, EP);
}

// Round 6
// 610.247 us; speedup vs baseline: 2.4234x; 1.1267x over previous
//
#include <hip/hip_runtime.h>

#define FIN 128
#define H1_ 50
#define H2_ 10

#define BKT_SHIFT 7
#define BKT_W 128              // nodes per bucket
#define NB_MAX 800             // >= ceil(100000/128) = 782
#define P1_CHUNK 8192          // edges per block in partition pass

// ---------------- bf16 helpers (RNE) ----------------

__device__ inline float bf2f(unsigned int u16) {
    union { unsigned int i; float f; } c; c.i = u16 << 16; return c.f;
}
__device__ inline unsigned short f2bf(float f) {
    union { float f; unsigned int i; } c; c.f = f;
    unsigned int x = c.i;
    return (unsigned short)((x + 0x7FFFu + ((x >> 16) & 1u)) >> 16);
}

// ================= CSR build: hist + scan =================

__global__ void hist_kernel(const int* __restrict__ dst, int* __restrict__ cnt, int E) {
    int e = blockIdx.x * blockDim.x + threadIdx.x;
    if (e < E) atomicAdd(&cnt[dst[e]], 1);
}

__global__ __launch_bounds__(256) void scan_block(const int* __restrict__ cnt,
                                                  int* __restrict__ rowptr,
                                                  int* __restrict__ partials, int N) {
    __shared__ int sSum[256];
    int t = threadIdx.x;
    int base = blockIdx.x * 1024 + t * 4;
    int v0 = (base + 0 < N) ? cnt[base + 0] : 0;
    int v1 = (base + 1 < N) ? cnt[base + 1] : 0;
    int v2 = (base + 2 < N) ? cnt[base + 2] : 0;
    int v3 = (base + 3 < N) ? cnt[base + 3] : 0;
    int tsum = v0 + v1 + v2 + v3;
    sSum[t] = tsum;
    __syncthreads();
    for (int off = 1; off < 256; off <<= 1) {
        int x = (t >= off) ? sSum[t - off] : 0;
        __syncthreads();
        sSum[t] += x;
        __syncthreads();
    }
    int excl = sSum[t] - tsum;
    if (t == 255) partials[blockIdx.x] = sSum[255];
    if (base + 0 < N) rowptr[base + 0] = excl;
    excl += v0;
    if (base + 1 < N) rowptr[base + 1] = excl;
    excl += v1;
    if (base + 2 < N) rowptr[base + 2] = excl;
    excl += v2;
    if (base + 3 < N) rowptr[base + 3] = excl;
}

__global__ void scan_partials(int* __restrict__ partials, int nb) {
    __shared__ int s[128];
    int t = threadIdx.x;
    int v = (t < nb) ? partials[t] : 0;
    s[t] = v;
    __syncthreads();
    for (int off = 1; off < 128; off <<= 1) {
        int x = (t >= off) ? s[t - off] : 0;
        __syncthreads();
        s[t] += x;
        __syncthreads();
    }
    if (t < nb) partials[t] = s[t] - v;
}

__global__ void finalize_kernel(const int* __restrict__ cnt, int* __restrict__ rowptr,
                                const int* __restrict__ partials, float* __restrict__ dinv,
                                int N, int E) {
    int i = blockIdx.x * blockDim.x + threadIdx.x;
    if (i == 0) rowptr[N] = E;
    if (i >= N) return;
    dinv[i] = rsqrtf(1.0f + (float)cnt[i]);     // deg includes self-loop
    rowptr[i] += partials[i >> 10];
}

__global__ void init_bcursor(const int* __restrict__ rowptr, int* __restrict__ bcursor, int nb2) {
    int b = blockIdx.x * blockDim.x + threadIdx.x;
    if (b < nb2) bcursor[b] = rowptr[b << BKT_SHIFT];
}

// ================= pass 1: partition edges into 128-node buckets =================
// packed record: src (bits 0..16) | dst-within-bucket (bits 17..23)

__global__ __launch_bounds__(256) void partition_pass1(const int* __restrict__ src,
                                                       const int* __restrict__ dst,
                                                       int* __restrict__ bcursor,
                                                       int* __restrict__ pairbuf, int E) {
    __shared__ int lhist[NB_MAX];
    __shared__ int lbase[NB_MAX];
    int tid = threadIdx.x;
    for (int i = tid; i < NB_MAX; i += 256) lhist[i] = 0;
    __syncthreads();
    int lo = blockIdx.x * P1_CHUNK;
    int hi = min(lo + P1_CHUNK, E);
    for (int e = lo + tid; e < hi; e += 256)
        atomicAdd(&lhist[dst[e] >> BKT_SHIFT], 1);
    __syncthreads();
    for (int b = tid; b < NB_MAX; b += 256) {
        int c = lhist[b];
        lbase[b] = c ? atomicAdd(&bcursor[b], c) : 0;
    }
    __syncthreads();
    for (int i = tid; i < NB_MAX; i += 256) lhist[i] = 0;   // reuse as local cursor
    __syncthreads();
    for (int e = lo + tid; e < hi; e += 256) {
        int s = src[e], d = dst[e];
        int b = d >> BKT_SHIFT;
        int r = atomicAdd(&lhist[b], 1);
        pairbuf[lbase[b] + r] = s | ((d & (BKT_W - 1)) << 17);
    }
}

// ================= pass 2: within-bucket fill =================

__global__ __launch_bounds__(256) void bucket_fill(const int* __restrict__ pairbuf,
                                                   const int* __restrict__ rowptr,
                                                   int* __restrict__ ecol, int N) {
    __shared__ int cur[BKT_W];
    int b = blockIdx.x;
    int base_node = b << BKT_SHIFT;
    int nnodes = min(BKT_W, N - base_node);
    int tid = threadIdx.x;
    if (tid < nnodes) cur[tid] = rowptr[base_node + tid];
    __syncthreads();
    int start = rowptr[base_node];
    int endp  = rowptr[min(base_node + BKT_W, N)];
    for (int j = start + tid; j < endp; j += 256) {
        int p = pairbuf[j];
        int pos = atomicAdd(&cur[p >> 17], 1);
        ecol[pos] = p & 0x1FFFF;
    }
}

// ============ GEMM1: st1p[N,64] (bf16, padded) = (x @ W1) * dinv[node] ============

#define G1_NODES 16
__global__ __launch_bounds__(256) void gemm1_kernel(const float* __restrict__ x,
                                                    const float* __restrict__ W1,
                                                    const float* __restrict__ dinv,
                                                    unsigned short* __restrict__ st1p, int N) {
    __shared__ float sW[FIN * H1_];        // [k][f], 25.6 KB
    __shared__ float sX[G1_NODES * FIN];   // 8 KB
    int tid = threadIdx.x;
    {
        const float4* W4 = (const float4*)W1;
        float4* sW4 = (float4*)sW;
        for (int i = tid; i < FIN * H1_ / 4; i += 256) sW4[i] = W4[i];
        const float4* x4 = (const float4*)(x + (size_t)blockIdx.x * G1_NODES * FIN);
        float4* sX4 = (float4*)sX;
        for (int i = tid; i < G1_NODES * FIN / 4; i += 256) sX4[i] = x4[i];
    }
    __syncthreads();
    int nb = blockIdx.x * G1_NODES;
    for (int oi = tid; oi < G1_NODES * H1_; oi += 256) {
        int ln = oi / H1_;
        int f  = oi - ln * H1_;
        const float* xr = &sX[ln * FIN];
        float acc = 0.0f;
#pragma unroll 16
        for (int k = 0; k < FIN; ++k) acc = fmaf(xr[k], sW[k * H1_ + f], acc);
        st1p[(size_t)(nb + ln) * 64 + f] = f2bf(acc * dinv[nb + ln]);
    }
}

// ============ aggregate layer 1: bf16 gather, fp32 accumulate ============
// 25 threads/node, 2 feats each (ushort2). out1 = relu(dinv[d]*sum + b)

#define F2 25
__global__ __launch_bounds__(256) void csr_aggregate1(const unsigned short* __restrict__ st,
                                                      const int* __restrict__ rowptr,
                                                      const int* __restrict__ ecol,
                                                      const float* __restrict__ dinv,
                                                      const float* __restrict__ b,
                                                      float* __restrict__ out, int N) {
    int idx = blockIdx.x * blockDim.x + threadIdx.x;
    if (idx >= N * F2) return;
    int d  = idx / F2;
    int fp = idx - d * F2;
    int fo = 2 * fp;
    unsigned int self2 = *(const unsigned int*)(st + (size_t)d * 64 + fo);
    float acc0 = bf2f(self2 & 0xFFFFu);
    float acc1 = bf2f(self2 >> 16);
    int j = rowptr[d], end = rowptr[d + 1];
    for (; j + 3 < end; j += 4) {
        int s0 = ecol[j], s1 = ecol[j + 1], s2 = ecol[j + 2], s3 = ecol[j + 3];
        unsigned int v0 = *(const unsigned int*)(st + (size_t)s0 * 64 + fo);
        unsigned int v1 = *(const unsigned int*)(st + (size_t)s1 * 64 + fo);
        unsigned int v2 = *(const unsigned int*)(st + (size_t)s2 * 64 + fo);
        unsigned int v3 = *(const unsigned int*)(st + (size_t)s3 * 64 + fo);
        acc0 += (bf2f(v0 & 0xFFFFu) + bf2f(v1 & 0xFFFFu)) + (bf2f(v2 & 0xFFFFu) + bf2f(v3 & 0xFFFFu));
        acc1 += (bf2f(v0 >> 16) + bf2f(v1 >> 16)) + (bf2f(v2 >> 16) + bf2f(v3 >> 16));
    }
    for (; j < end; ++j) {
        unsigned int v = *(const unsigned int*)(st + (size_t)ecol[j] * 64 + fo);
        acc0 += bf2f(v & 0xFFFFu);
        acc1 += bf2f(v >> 16);
    }
    float vd = dinv[d];
    float r0 = fmaxf(fmaf(vd, acc0, b[fo]),     0.0f);
    float r1 = fmaxf(fmaf(vd, acc1, b[fo + 1]), 0.0f);
    *(float2*)(out + (size_t)d * H1_ + fo) = make_float2(r0, r1);
}

// ================= GEMM2: st2[N,10] = (h @ W2) * dinv[node] =================

__global__ __launch_bounds__(256) void gemm2_kernel(const float* __restrict__ h,
                                                    const float* __restrict__ W2,
                                                    const float* __restrict__ dinv,
                                                    float* __restrict__ st2, int n) {
    __shared__ float sW[H1_ * H2_];   // 2 KB
    int tid = threadIdx.x;
    for (int i = tid; i < H1_ * H2_; i += 256) sW[i] = W2[i];
    __syncthreads();
    int idx = blockIdx.x * blockDim.x + tid;
    if (idx >= n) return;
    int node = idx / H2_;
    int f    = idx - node * H2_;
    const float* hr = &h[node * H1_];
    float acc = 0.0f;
#pragma unroll
    for (int k = 0; k < H1_; ++k) acc = fmaf(hr[k], sW[k * H2_ + f], acc);
    st2[idx] = acc * dinv[node];
}

// ============ aggregate layer 2 (fp32, F=10) ============

template <int F, bool RELU>
__global__ __launch_bounds__(256) void csr_aggregate(const float* __restrict__ st,
                                                     const int* __restrict__ rowptr,
                                                     const int* __restrict__ ecol,
                                                     const float* __restrict__ dinv,
                                                     const float* __restrict__ b,
                                                     float* __restrict__ out, int N) {
    int idx = blockIdx.x * blockDim.x + threadIdx.x;
    if (idx >= N * F) return;
    int d = idx / F;
    int f = idx - d * F;
    float acc = st[idx];            // self-loop term
    int j = rowptr[d], end = rowptr[d + 1];
    for (; j + 3 < end; j += 4) {
        int s0 = ecol[j], s1 = ecol[j + 1], s2 = ecol[j + 2], s3 = ecol[j + 3];
        float a0 = st[s0 * F + f], a1 = st[s1 * F + f];
        float a2 = st[s2 * F + f], a3 = st[s3 * F + f];
        acc += (a0 + a1) + (a2 + a3);
    }
    for (; j < end; ++j) acc += st[ecol[j] * F + f];
    float v = fmaf(dinv[d], acc, b[f]);
    out[idx] = RELU ? fmaxf(v, 0.0f) : v;
}

// ================= decode =================

__global__ void decode_kernel(const float* __restrict__ z, const int* __restrict__ pos,
                              const int* __restrict__ neg, float* __restrict__ logits, int EP) {
    int i = blockIdx.x * blockDim.x + threadIdx.x;
    if (i >= 2 * EP) return;
    int a, b;
    if (i < EP) { a = pos[i]; b = pos[EP + i]; }
    else        { int j = i - EP; a = neg[j]; b = neg[EP + j]; }
    const float* za = &z[a * H2_];
    const float* zb = &z[b * H2_];
    float acc = 0.0f;
#pragma unroll
    for (int f = 0; f < H2_; ++f) acc = fmaf(za[f], zb[f], acc);
    logits[i] = acc;
}

// ================= launch =================

extern "C" void kernel_launch(void* const* d_in, const int* in_sizes, int n_in,
                              void* d_out, int out_size, void* d_ws, size_t ws_size,
                              hipStream_t stream) {
    const float* x   = (const float*)d_in[0];
    const float* W1  = (const float*)d_in[1];
    const float* b1  = (const float*)d_in[2];
    const float* W2  = (const float*)d_in[3];
    const float* b2  = (const float*)d_in[4];
    const int* train = (const int*)d_in[5];
    const int* pos   = (const int*)d_in[6];
    const int* neg   = (const int*)d_in[7];

    const int N  = in_sizes[0] / FIN;       // 100000
    const int E  = in_sizes[5] / 2;         // 3200000
    const int EP = in_sizes[6] / 2;         // 1600000

    const int* tsrc = train;
    const int* tdst = train + E;

    // ---- workspace layout (~34.1 MB peak) ----
    // ints: cnt[N] | rowptr[N+2] | partials[128] | bcursor[1024]
    // floats: dinv[N]
    // regA = 32N floats (128N B): st1p bf16[N*64] (=128N B exactly);
    //        after agg1 st1p dies -> st2[10N] | out2[10N] (20N floats, fits)
    // regB = 50N floats: out1[50N]; pairbuf int[E=32N] overlays (dead before agg1)
    size_t off = 0;
    int* cnt      = (int*)d_ws;              off += N;
    int* rowptr   = (int*)d_ws + off;        off += (size_t)N + 2;
    int* partials = (int*)d_ws + off;        off += 128;
    int* bcursor  = (int*)d_ws + off;        off += 1024;
    float* dinv   = (float*)d_ws + off;      off += N;
    off = (off + 3) & ~(size_t)3;            // 16B-align
    float* regA   = (float*)d_ws + off;      off += (size_t)32 * N;   // 32N floats = 128N bytes
    float* regB   = (float*)d_ws + off;      // 50N floats
    unsigned short* st1p = (unsigned short*)regA;   // 64N ushorts = 128N bytes, fits exactly
    float* st2    = regA;                            // overlays st1p after agg1
    float* out2   = regA + (size_t)10 * N;           // z, regA[10N..20N) < 32N  OK
    float* out1   = regB;                            // h after relu, 50N floats
    int* pairbuf  = (int*)regB;                      // E = 32N ints <= 50N, dead before agg1
    int* ecol     = (int*)d_out;                     // E ints; dead before decode
    float* logits = (float*)d_out;

    const int NB2 = (N + BKT_W - 1) >> BKT_SHIFT;   // 782 <= NB_MAX

    // ---- CSR build ----
    hipMemsetAsync(cnt, 0, (size_t)N * sizeof(int), stream);
    hist_kernel<<<(E + 255) / 256, 256, 0, stream>>>(tdst, cnt, E);
    int nb = (N + 1023) / 1024;               // 98 <= 128
    scan_block<<<nb, 256, 0, stream>>>(cnt, rowptr, partials, N);
    scan_partials<<<1, 128, 0, stream>>>(partials, nb);
    finalize_kernel<<<(N + 255) / 256, 256, 0, stream>>>(cnt, rowptr, partials, dinv, N, E);
    init_bcursor<<<(NB2 + 255) / 256, 256, 0, stream>>>(rowptr, bcursor, NB2);
    partition_pass1<<<(E + P1_CHUNK - 1) / P1_CHUNK, 256, 0, stream>>>(tsrc, tdst, bcursor, pairbuf, E);
    bucket_fill<<<NB2, 256, 0, stream>>>(pairbuf, rowptr, ecol, N);

    // ---- layer 1 ----
    gemm1_kernel<<<(N + G1_NODES - 1) / G1_NODES, 256, 0, stream>>>(x, W1, dinv, st1p, N);
    csr_aggregate1<<<(N * F2 + 255) / 256, 256, 0, stream>>>(
        st1p, rowptr, ecol, dinv, b1, out1, N);

    // ---- layer 2 ----
    gemm2_kernel<<<(N * H2_ + 255) / 256, 256, 0, stream>>>(out1, W2, dinv, st2, N * H2_);
    csr_aggregate<H2_, false><<<(N * H2_ + 255) / 256, 256, 0, stream>>>(
        st2, rowptr, ecol, dinv, b2, out2, N);

    // ---- decode ----
    decode_kernel<<<(2 * EP + 255) / 256, 256, 0, stream>>>(out2, pos, neg, logits, EP);
}

// Round 7
// 502.170 us; speedup vs baseline: 2.9449x; 1.2152x over previous
//
#include <hip/hip_runtime.h>

#define FIN 128
#define H1_ 50
#define H2_ 10

#define BKT_SHIFT 7
#define BKT_W 128              // nodes per bucket
#define NB_MAX 800             // >= ceil(100000/128) = 782
#define P1_CHUNK 8192          // edges per block in partition pass

// ---------------- bf16 helpers (RNE) ----------------

__device__ inline float bf2f(unsigned int u16) {
    union { unsigned int i; float f; } c; c.i = u16 << 16; return c.f;
}
__device__ inline unsigned short f2bf(float f) {
    union { float f; unsigned int i; } c; c.f = f;
    unsigned int x = c.i;
    return (unsigned short)((x + 0x7FFFu + ((x >> 16) & 1u)) >> 16);
}

// ================= bucket-level histogram (LDS-staged) =================

__global__ __launch_bounds__(256) void bucket_count(const int* __restrict__ dst,
                                                    int* __restrict__ bcnt, int E) {
    __shared__ int lh[NB_MAX];
    int tid = threadIdx.x;
    for (int i = tid; i < NB_MAX; i += 256) lh[i] = 0;
    __syncthreads();
    int lo = blockIdx.x * P1_CHUNK;
    int hi = min(lo + P1_CHUNK, E);
    for (int e = lo + tid; e < hi; e += 256)
        atomicAdd(&lh[dst[e] >> BKT_SHIFT], 1);
    __syncthreads();
    for (int b = tid; b < NB_MAX; b += 256) {
        int c = lh[b];
        if (c) atomicAdd(&bcnt[b], c);
    }
}

// single block: exclusive scan of nb2 (<=1024) bucket counts -> bbase, bcursor
__global__ __launch_bounds__(256) void bucket_scan(const int* __restrict__ bcnt,
                                                   int* __restrict__ bbase,
                                                   int* __restrict__ bcursor,
                                                   int nb2, int E) {
    __shared__ int s[256];
    int t = threadIdx.x;
    int base = t * 4;
    int v0 = (base + 0 < nb2) ? bcnt[base + 0] : 0;
    int v1 = (base + 1 < nb2) ? bcnt[base + 1] : 0;
    int v2 = (base + 2 < nb2) ? bcnt[base + 2] : 0;
    int v3 = (base + 3 < nb2) ? bcnt[base + 3] : 0;
    int tsum = v0 + v1 + v2 + v3;
    s[t] = tsum;
    __syncthreads();
    for (int off = 1; off < 256; off <<= 1) {
        int x = (t >= off) ? s[t - off] : 0;
        __syncthreads();
        s[t] += x;
        __syncthreads();
    }
    int excl = s[t] - tsum;
    if (t == 0) bbase[nb2] = E;
    if (base + 0 < nb2) { bbase[base + 0] = excl; bcursor[base + 0] = excl; }
    excl += v0;
    if (base + 1 < nb2) { bbase[base + 1] = excl; bcursor[base + 1] = excl; }
    excl += v1;
    if (base + 2 < nb2) { bbase[base + 2] = excl; bcursor[base + 2] = excl; }
    excl += v2;
    if (base + 3 < nb2) { bbase[base + 3] = excl; bcursor[base + 3] = excl; }
}

// ================= pass 1: partition edges into 128-node buckets =================
// packed record: src (bits 0..16) | dst-within-bucket (bits 17..23)

__global__ __launch_bounds__(256) void partition_pass1(const int* __restrict__ src,
                                                       const int* __restrict__ dst,
                                                       int* __restrict__ bcursor,
                                                       int* __restrict__ pairbuf, int E) {
    __shared__ int lhist[NB_MAX];
    __shared__ int lbase[NB_MAX];
    int tid = threadIdx.x;
    for (int i = tid; i < NB_MAX; i += 256) lhist[i] = 0;
    __syncthreads();
    int lo = blockIdx.x * P1_CHUNK;
    int hi = min(lo + P1_CHUNK, E);
    for (int e = lo + tid; e < hi; e += 256)
        atomicAdd(&lhist[dst[e] >> BKT_SHIFT], 1);
    __syncthreads();
    for (int b = tid; b < NB_MAX; b += 256) {
        int c = lhist[b];
        lbase[b] = c ? atomicAdd(&bcursor[b], c) : 0;
    }
    __syncthreads();
    for (int i = tid; i < NB_MAX; i += 256) lhist[i] = 0;   // reuse as local cursor
    __syncthreads();
    for (int e = lo + tid; e < hi; e += 256) {
        int s = src[e], d = dst[e];
        int b = d >> BKT_SHIFT;
        int r = atomicAdd(&lhist[b], 1);
        pairbuf[lbase[b] + r] = s | ((d & (BKT_W - 1)) << 17);
    }
}

// ========== pass 2: per-bucket count + scan + rowptr/dinv + fill (fused) ==========

__global__ __launch_bounds__(256) void bucket_fill_scan(const int* __restrict__ pairbuf,
                                                        const int* __restrict__ bbase,
                                                        int* __restrict__ rowptr,
                                                        float* __restrict__ dinv,
                                                        int* __restrict__ ecol,
                                                        int N, int E) {
    __shared__ int cnt[BKT_W];
    __shared__ int sc[BKT_W];
    __shared__ int cur[BKT_W];
    int b = blockIdx.x;
    int base_node = b << BKT_SHIFT;
    int nnodes = min(BKT_W, N - base_node);
    int tid = threadIdx.x;
    if (tid < BKT_W) cnt[tid] = 0;
    __syncthreads();
    int lo = bbase[b], hi = bbase[b + 1];
    // pass A: per-node counts
    for (int j = lo + tid; j < hi; j += 256)
        atomicAdd(&cnt[pairbuf[j] >> 17], 1);
    __syncthreads();
    int c = (tid < BKT_W) ? cnt[tid] : 0;
    if (tid < BKT_W) sc[tid] = c;
    __syncthreads();
    for (int off = 1; off < BKT_W; off <<= 1) {
        int xv = (tid >= off && tid < BKT_W) ? sc[tid - off] : 0;
        __syncthreads();
        if (tid < BKT_W) sc[tid] += xv;
        __syncthreads();
    }
    if (tid < nnodes) {
        int rp = lo + sc[tid] - c;           // exclusive prefix within bucket
        rowptr[base_node + tid] = rp;
        cur[tid] = rp;
        dinv[base_node + tid] = rsqrtf(1.0f + (float)c);   // deg incl self-loop
    }
    __syncthreads();
    // pass B: scatter into contiguous CSR segment (single-writer dense lines)
    for (int j = lo + tid; j < hi; j += 256) {
        int p = pairbuf[j];
        int pos = atomicAdd(&cur[p >> 17], 1);
        ecol[pos] = p & 0x1FFFF;
    }
    if (b == (int)gridDim.x - 1 && tid == 0) rowptr[N] = E;
}

// ============ GEMM1: st1p[N,64] (bf16, padded) = (x @ W1) * dinv[node] ============

#define G1_NODES 16
__global__ __launch_bounds__(256) void gemm1_kernel(const float* __restrict__ x,
                                                    const float* __restrict__ W1,
                                                    const float* __restrict__ dinv,
                                                    unsigned short* __restrict__ st1p, int N) {
    __shared__ float sW[FIN * H1_];        // [k][f], 25.6 KB
    __shared__ float sX[G1_NODES * FIN];   // 8 KB
    int tid = threadIdx.x;
    {
        const float4* W4 = (const float4*)W1;
        float4* sW4 = (float4*)sW;
        for (int i = tid; i < FIN * H1_ / 4; i += 256) sW4[i] = W4[i];
        const float4* x4 = (const float4*)(x + (size_t)blockIdx.x * G1_NODES * FIN);
        float4* sX4 = (float4*)sX;
        for (int i = tid; i < G1_NODES * FIN / 4; i += 256) sX4[i] = x4[i];
    }
    __syncthreads();
    int nb = blockIdx.x * G1_NODES;
    for (int oi = tid; oi < G1_NODES * H1_; oi += 256) {
        int ln = oi / H1_;
        int f  = oi - ln * H1_;
        const float* xr = &sX[ln * FIN];
        float acc = 0.0f;
#pragma unroll 16
        for (int k = 0; k < FIN; ++k) acc = fmaf(xr[k], sW[k * H1_ + f], acc);
        st1p[(size_t)(nb + ln) * 64 + f] = f2bf(acc * dinv[nb + ln]);
    }
}

// ============ aggregate layer 1: bf16 gather, fp32 accumulate ============

#define F2 25
__global__ __launch_bounds__(256) void csr_aggregate1(const unsigned short* __restrict__ st,
                                                      const int* __restrict__ rowptr,
                                                      const int* __restrict__ ecol,
                                                      const float* __restrict__ dinv,
                                                      const float* __restrict__ b,
                                                      float* __restrict__ out, int N) {
    int idx = blockIdx.x * blockDim.x + threadIdx.x;
    if (idx >= N * F2) return;
    int d  = idx / F2;
    int fp = idx - d * F2;
    int fo = 2 * fp;
    unsigned int self2 = *(const unsigned int*)(st + (size_t)d * 64 + fo);
    float acc0 = bf2f(self2 & 0xFFFFu);
    float acc1 = bf2f(self2 >> 16);
    int j = rowptr[d], end = rowptr[d + 1];
    for (; j + 3 < end; j += 4) {
        int s0 = ecol[j], s1 = ecol[j + 1], s2 = ecol[j + 2], s3 = ecol[j + 3];
        unsigned int v0 = *(const unsigned int*)(st + (size_t)s0 * 64 + fo);
        unsigned int v1 = *(const unsigned int*)(st + (size_t)s1 * 64 + fo);
        unsigned int v2 = *(const unsigned int*)(st + (size_t)s2 * 64 + fo);
        unsigned int v3 = *(const unsigned int*)(st + (size_t)s3 * 64 + fo);
        acc0 += (bf2f(v0 & 0xFFFFu) + bf2f(v1 & 0xFFFFu)) + (bf2f(v2 & 0xFFFFu) + bf2f(v3 & 0xFFFFu));
        acc1 += (bf2f(v0 >> 16) + bf2f(v1 >> 16)) + (bf2f(v2 >> 16) + bf2f(v3 >> 16));
    }
    for (; j < end; ++j) {
        unsigned int v = *(const unsigned int*)(st + (size_t)ecol[j] * 64 + fo);
        acc0 += bf2f(v & 0xFFFFu);
        acc1 += bf2f(v >> 16);
    }
    float vd = dinv[d];
    float r0 = fmaxf(fmaf(vd, acc0, b[fo]),     0.0f);
    float r1 = fmaxf(fmaf(vd, acc1, b[fo + 1]), 0.0f);
    *(float2*)(out + (size_t)d * H1_ + fo) = make_float2(r0, r1);
}

// ================= GEMM2: st2[N,10] = (h @ W2) * dinv[node] =================

__global__ __launch_bounds__(256) void gemm2_kernel(const float* __restrict__ h,
                                                    const float* __restrict__ W2,
                                                    const float* __restrict__ dinv,
                                                    float* __restrict__ st2, int n) {
    __shared__ float sW[H1_ * H2_];   // 2 KB
    int tid = threadIdx.x;
    for (int i = tid; i < H1_ * H2_; i += 256) sW[i] = W2[i];
    __syncthreads();
    int idx = blockIdx.x * blockDim.x + tid;
    if (idx >= n) return;
    int node = idx / H2_;
    int f    = idx - node * H2_;
    const float* hr = &h[node * H1_];
    float acc = 0.0f;
#pragma unroll
    for (int k = 0; k < H1_; ++k) acc = fmaf(hr[k], sW[k * H2_ + f], acc);
    st2[idx] = acc * dinv[node];
}

// ============ aggregate layer 2 (fp32, F=10) ============

template <int F, bool RELU>
__global__ __launch_bounds__(256) void csr_aggregate(const float* __restrict__ st,
                                                     const int* __restrict__ rowptr,
                                                     const int* __restrict__ ecol,
                                                     const float* __restrict__ dinv,
                                                     const float* __restrict__ b,
                                                     float* __restrict__ out, int N) {
    int idx = blockIdx.x * blockDim.x + threadIdx.x;
    if (idx >= N * F) return;
    int d = idx / F;
    int f = idx - d * F;
    float acc = st[idx];            // self-loop term
    int j = rowptr[d], end = rowptr[d + 1];
    for (; j + 3 < end; j += 4) {
        int s0 = ecol[j], s1 = ecol[j + 1], s2 = ecol[j + 2], s3 = ecol[j + 3];
        float a0 = st[s0 * F + f], a1 = st[s1 * F + f];
        float a2 = st[s2 * F + f], a3 = st[s3 * F + f];
        acc += (a0 + a1) + (a2 + a3);
    }
    for (; j < end; ++j) acc += st[ecol[j] * F + f];
    float v = fmaf(dinv[d], acc, b[f]);
    out[idx] = RELU ? fmaxf(v, 0.0f) : v;
}

// ================= decode =================

__global__ void decode_kernel(const float* __restrict__ z, const int* __restrict__ pos,
                              const int* __restrict__ neg, float* __restrict__ logits, int EP) {
    int i = blockIdx.x * blockDim.x + threadIdx.x;
    if (i >= 2 * EP) return;
    int a, b;
    if (i < EP) { a = pos[i]; b = pos[EP + i]; }
    else        { int j = i - EP; a = neg[j]; b = neg[EP + j]; }
    const float* za = &z[a * H2_];
    const float* zb = &z[b * H2_];
    float acc = 0.0f;
#pragma unroll
    for (int f = 0; f < H2_; ++f) acc = fmaf(za[f], zb[f], acc);
    logits[i] = acc;
}

// ================= launch =================

extern "C" void kernel_launch(void* const* d_in, const int* in_sizes, int n_in,
                              void* d_out, int out_size, void* d_ws, size_t ws_size,
                              hipStream_t stream) {
    const float* x   = (const float*)d_in[0];
    const float* W1  = (const float*)d_in[1];
    const float* b1  = (const float*)d_in[2];
    const float* W2  = (const float*)d_in[3];
    const float* b2  = (const float*)d_in[4];
    const int* train = (const int*)d_in[5];
    const int* pos   = (const int*)d_in[6];
    const int* neg   = (const int*)d_in[7];

    const int N  = in_sizes[0] / FIN;       // 100000
    const int E  = in_sizes[5] / 2;         // 3200000
    const int EP = in_sizes[6] / 2;         // 1600000

    const int* tsrc = train;
    const int* tdst = train + E;

    // ---- workspace layout (~33.6 MB peak) ----
    // ints: rowptr[N+1] | bcnt[NB_MAX] | bbase[NB_MAX+1] | bcursor[NB_MAX]
    // floats: dinv[N]
    // regA = 32N floats: st1p bf16[N*64]; after agg1 -> st2[10N] | out2[10N]
    // regB = 50N floats: out1[50N]; pairbuf int[E=32N] overlays (dead before agg1)
    size_t off = 0;
    int* rowptr   = (int*)d_ws;              off += (size_t)N + 1;
    int* bcnt     = (int*)d_ws + off;        off += NB_MAX;
    int* bbase    = (int*)d_ws + off;        off += NB_MAX + 1;
    int* bcursor  = (int*)d_ws + off;        off += NB_MAX;
    float* dinv   = (float*)d_ws + off;      off += N;
    off = (off + 3) & ~(size_t)3;            // 16B-align
    float* regA   = (float*)d_ws + off;      off += (size_t)32 * N;
    float* regB   = (float*)d_ws + off;
    unsigned short* st1p = (unsigned short*)regA;   // 64N ushorts = 128N bytes
    float* st2    = regA;                            // overlays st1p after agg1
    float* out2   = regA + (size_t)10 * N;           // z
    float* out1   = regB;                            // h after relu, 50N floats
    int* pairbuf  = (int*)regB;                      // E = 32N ints, dead before agg1
    int* ecol     = (int*)d_out;                     // E ints; dead before decode
    float* logits = (float*)d_out;

    const int NB2 = (N + BKT_W - 1) >> BKT_SHIFT;   // 782 <= NB_MAX
    const int P1B = (E + P1_CHUNK - 1) / P1_CHUNK;  // 391

    // ---- CSR build (no node-level global atomics anywhere) ----
    hipMemsetAsync(bcnt, 0, NB_MAX * sizeof(int), stream);
    bucket_count<<<P1B, 256, 0, stream>>>(tdst, bcnt, E);
    bucket_scan<<<1, 256, 0, stream>>>(bcnt, bbase, bcursor, NB2, E);
    partition_pass1<<<P1B, 256, 0, stream>>>(tsrc, tdst, bcursor, pairbuf, E);
    bucket_fill_scan<<<NB2, 256, 0, stream>>>(pairbuf, bbase, rowptr, dinv, ecol, N, E);

    // ---- layer 1 ----
    gemm1_kernel<<<(N + G1_NODES - 1) / G1_NODES, 256, 0, stream>>>(x, W1, dinv, st1p, N);
    csr_aggregate1<<<(N * F2 + 255) / 256, 256, 0, stream>>>(
        st1p, rowptr, ecol, dinv, b1, out1, N);

    // ---- layer 2 ----
    gemm2_kernel<<<(N * H2_ + 255) / 256, 256, 0, stream>>>(out1, W2, dinv, st2, N * H2_);
    csr_aggregate<H2_, false><<<(N * H2_ + 255) / 256, 256, 0, stream>>>(
        st2, rowptr, ecol, dinv, b2, out2, N);

    // ---- decode ----
    decode_kernel<<<(2 * EP + 255) / 256, 256, 0, stream>>>(out2, pos, neg, logits, EP);
}

// Round 8
// 476.401 us; speedup vs baseline: 3.1042x; 1.0541x over previous
//
#include <hip/hip_runtime.h>

#define FIN 128
#define H1_ 50
#define H2_ 10

#define BKT_SHIFT 7
#define BKT_W 128              // nodes per bucket
#define NB_MAX 800             // >= ceil(100000/128) = 782
#define P1_CHUNK 8192          // edges per block in partition pass

// ---------------- bf16 helpers (RNE) ----------------

__device__ inline float bf2f(unsigned int u16) {
    union { unsigned int i; float f; } c; c.i = u16 << 16; return c.f;
}
__device__ inline unsigned short f2bf(float f) {
    union { float f; unsigned int i; } c; c.f = f;
    unsigned int x = c.i;
    return (unsigned short)((x + 0x7FFFu + ((x >> 16) & 1u)) >> 16);
}

// ================= bucket-level histogram (LDS-staged) =================

__global__ __launch_bounds__(256) void bucket_count(const int* __restrict__ dst,
                                                    int* __restrict__ bcnt, int E) {
    __shared__ int lh[NB_MAX];
    int tid = threadIdx.x;
    for (int i = tid; i < NB_MAX; i += 256) lh[i] = 0;
    __syncthreads();
    int lo = blockIdx.x * P1_CHUNK;
    int hi = min(lo + P1_CHUNK, E);
    for (int e = lo + tid; e < hi; e += 256)
        atomicAdd(&lh[dst[e] >> BKT_SHIFT], 1);
    __syncthreads();
    for (int b = tid; b < NB_MAX; b += 256) {
        int c = lh[b];
        if (c) atomicAdd(&bcnt[b], c);
    }
}

// single block: exclusive scan of nb2 (<=1024) bucket counts -> bbase, bcursor
__global__ __launch_bounds__(256) void bucket_scan(const int* __restrict__ bcnt,
                                                   int* __restrict__ bbase,
                                                   int* __restrict__ bcursor,
                                                   int nb2, int E) {
    __shared__ int s[256];
    int t = threadIdx.x;
    int base = t * 4;
    int v0 = (base + 0 < nb2) ? bcnt[base + 0] : 0;
    int v1 = (base + 1 < nb2) ? bcnt[base + 1] : 0;
    int v2 = (base + 2 < nb2) ? bcnt[base + 2] : 0;
    int v3 = (base + 3 < nb2) ? bcnt[base + 3] : 0;
    int tsum = v0 + v1 + v2 + v3;
    s[t] = tsum;
    __syncthreads();
    for (int off = 1; off < 256; off <<= 1) {
        int x = (t >= off) ? s[t - off] : 0;
        __syncthreads();
        s[t] += x;
        __syncthreads();
    }
    int excl = s[t] - tsum;
    if (t == 0) bbase[nb2] = E;
    if (base + 0 < nb2) { bbase[base + 0] = excl; bcursor[base + 0] = excl; }
    excl += v0;
    if (base + 1 < nb2) { bbase[base + 1] = excl; bcursor[base + 1] = excl; }
    excl += v1;
    if (base + 2 < nb2) { bbase[base + 2] = excl; bcursor[base + 2] = excl; }
    excl += v2;
    if (base + 3 < nb2) { bbase[base + 3] = excl; bcursor[base + 3] = excl; }
}

// ================= pass 1: partition edges into 128-node buckets =================
// packed record: src (bits 0..16) | dst-within-bucket (bits 17..23)

__global__ __launch_bounds__(256) void partition_pass1(const int* __restrict__ src,
                                                       const int* __restrict__ dst,
                                                       int* __restrict__ bcursor,
                                                       int* __restrict__ pairbuf, int E) {
    __shared__ int lhist[NB_MAX];
    __shared__ int lbase[NB_MAX];
    int tid = threadIdx.x;
    for (int i = tid; i < NB_MAX; i += 256) lhist[i] = 0;
    __syncthreads();
    int lo = blockIdx.x * P1_CHUNK;
    int hi = min(lo + P1_CHUNK, E);
    for (int e = lo + tid; e < hi; e += 256)
        atomicAdd(&lhist[dst[e] >> BKT_SHIFT], 1);
    __syncthreads();
    for (int b = tid; b < NB_MAX; b += 256) {
        int c = lhist[b];
        lbase[b] = c ? atomicAdd(&bcursor[b], c) : 0;
    }
    __syncthreads();
    for (int i = tid; i < NB_MAX; i += 256) lhist[i] = 0;   // reuse as local cursor
    __syncthreads();
    for (int e = lo + tid; e < hi; e += 256) {
        int s = src[e], d = dst[e];
        int b = d >> BKT_SHIFT;
        int r = atomicAdd(&lhist[b], 1);
        pairbuf[lbase[b] + r] = s | ((d & (BKT_W - 1)) << 17);
    }
}

// ========== pass 2: per-bucket count + scan + rowptr/dinv + fill (fused) ==========

__global__ __launch_bounds__(256) void bucket_fill_scan(const int* __restrict__ pairbuf,
                                                        const int* __restrict__ bbase,
                                                        int* __restrict__ rowptr,
                                                        float* __restrict__ dinv,
                                                        int* __restrict__ ecol,
                                                        int N, int E) {
    __shared__ int cnt[BKT_W];
    __shared__ int sc[BKT_W];
    __shared__ int cur[BKT_W];
    int b = blockIdx.x;
    int base_node = b << BKT_SHIFT;
    int nnodes = min(BKT_W, N - base_node);
    int tid = threadIdx.x;
    if (tid < BKT_W) cnt[tid] = 0;
    __syncthreads();
    int lo = bbase[b], hi = bbase[b + 1];
    for (int j = lo + tid; j < hi; j += 256)
        atomicAdd(&cnt[pairbuf[j] >> 17], 1);
    __syncthreads();
    int c = (tid < BKT_W) ? cnt[tid] : 0;
    if (tid < BKT_W) sc[tid] = c;
    __syncthreads();
    for (int off = 1; off < BKT_W; off <<= 1) {
        int xv = (tid >= off && tid < BKT_W) ? sc[tid - off] : 0;
        __syncthreads();
        if (tid < BKT_W) sc[tid] += xv;
        __syncthreads();
    }
    if (tid < nnodes) {
        int rp = lo + sc[tid] - c;           // exclusive prefix within bucket
        rowptr[base_node + tid] = rp;
        cur[tid] = rp;
        dinv[base_node + tid] = rsqrtf(1.0f + (float)c);   // deg incl self-loop
    }
    __syncthreads();
    for (int j = lo + tid; j < hi; j += 256) {
        int p = pairbuf[j];
        int pos = atomicAdd(&cur[p >> 17], 1);
        ecol[pos] = p & 0x1FFFF;
    }
    if (b == (int)gridDim.x - 1 && tid == 0) rowptr[N] = E;
}

// ======== GEMM1 (register-tiled): st1p[N,64] bf16 = (x @ W1) * dinv[node] ========
// 32 nodes/block, 8 threads/node, 8 feats/thread (W cols padded 50->64 with zeros).
// sX rows padded to 132 words: bank offset 4*ln -> conflict-free x broadcast.

#define G1_NODES 32
#define SX_PITCH 132
__global__ __launch_bounds__(256) void gemm1_kernel(const float* __restrict__ x,
                                                    const float* __restrict__ W1,
                                                    const float* __restrict__ dinv,
                                                    unsigned short* __restrict__ st1p, int N) {
    __shared__ float sW[FIN * 64];            // 32 KB, [k][f64]
    __shared__ float sX[G1_NODES * SX_PITCH]; // 16.9 KB
    int tid = threadIdx.x;
    int nb = blockIdx.x * G1_NODES;
    for (int i = tid; i < FIN * 64; i += 256) {
        int k = i >> 6, f = i & 63;
        sW[i] = (f < H1_) ? W1[k * H1_ + f] : 0.0f;
    }
    {
        const float4* x4 = (const float4*)(x + (size_t)nb * FIN);
        for (int i = tid; i < G1_NODES * 32; i += 256) {   // 1024 float4 stages
            int ln = i >> 5, kk = i & 31;
            float4 v = (nb + ln < N) ? x4[(size_t)ln * 32 + kk]
                                     : make_float4(0.f, 0.f, 0.f, 0.f);
            *(float4*)(&sX[ln * SX_PITCH + kk * 4]) = v;
        }
    }
    __syncthreads();
    int ln = tid >> 3;        // 0..31
    int g  = tid & 7;         // 0..7
    int node = nb + ln;
    const float* xr = &sX[ln * SX_PITCH];
    const float* wc = &sW[g * 8];
    float acc[8] = {0, 0, 0, 0, 0, 0, 0, 0};
#pragma unroll 4
    for (int k = 0; k < FIN; ++k) {
        float xv = xr[k];
        const float* w = &wc[k * 64];
#pragma unroll
        for (int j = 0; j < 8; ++j) acc[j] = fmaf(xv, w[j], acc[j]);
    }
    if (node >= N) return;
    float di = dinv[node];
    unsigned short o[8];
#pragma unroll
    for (int j = 0; j < 8; ++j) o[j] = f2bf(acc[j] * di);
    uint4 pk;
    pk.x = (unsigned)o[0] | ((unsigned)o[1] << 16);
    pk.y = (unsigned)o[2] | ((unsigned)o[3] << 16);
    pk.z = (unsigned)o[4] | ((unsigned)o[5] << 16);
    pk.w = (unsigned)o[6] | ((unsigned)o[7] << 16);
    *(uint4*)(st1p + (size_t)node * 64 + g * 8) = pk;
}

// ============ aggregate layer 1: bf16 gather, fp32 accumulate ============

#define F2 25
__global__ __launch_bounds__(256) void csr_aggregate1(const unsigned short* __restrict__ st,
                                                      const int* __restrict__ rowptr,
                                                      const int* __restrict__ ecol,
                                                      const float* __restrict__ dinv,
                                                      const float* __restrict__ b,
                                                      float* __restrict__ out, int N) {
    int idx = blockIdx.x * blockDim.x + threadIdx.x;
    if (idx >= N * F2) return;
    int d  = idx / F2;
    int fp = idx - d * F2;
    int fo = 2 * fp;
    unsigned int self2 = *(const unsigned int*)(st + (size_t)d * 64 + fo);
    float acc0 = bf2f(self2 & 0xFFFFu);
    float acc1 = bf2f(self2 >> 16);
    int j = rowptr[d], end = rowptr[d + 1];
    for (; j + 3 < end; j += 4) {
        int s0 = ecol[j], s1 = ecol[j + 1], s2 = ecol[j + 2], s3 = ecol[j + 3];
        unsigned int v0 = *(const unsigned int*)(st + (size_t)s0 * 64 + fo);
        unsigned int v1 = *(const unsigned int*)(st + (size_t)s1 * 64 + fo);
        unsigned int v2 = *(const unsigned int*)(st + (size_t)s2 * 64 + fo);
        unsigned int v3 = *(const unsigned int*)(st + (size_t)s3 * 64 + fo);
        acc0 += (bf2f(v0 & 0xFFFFu) + bf2f(v1 & 0xFFFFu)) + (bf2f(v2 & 0xFFFFu) + bf2f(v3 & 0xFFFFu));
        acc1 += (bf2f(v0 >> 16) + bf2f(v1 >> 16)) + (bf2f(v2 >> 16) + bf2f(v3 >> 16));
    }
    for (; j < end; ++j) {
        unsigned int v = *(const unsigned int*)(st + (size_t)ecol[j] * 64 + fo);
        acc0 += bf2f(v & 0xFFFFu);
        acc1 += bf2f(v >> 16);
    }
    float vd = dinv[d];
    float r0 = fmaxf(fmaf(vd, acc0, b[fo]),     0.0f);
    float r1 = fmaxf(fmaf(vd, acc1, b[fo + 1]), 0.0f);
    *(float2*)(out + (size_t)d * H1_ + fo) = make_float2(r0, r1);
}

// ================= GEMM2: st2[N,10] = (h @ W2) * dinv[node] =================

__global__ __launch_bounds__(256) void gemm2_kernel(const float* __restrict__ h,
                                                    const float* __restrict__ W2,
                                                    const float* __restrict__ dinv,
                                                    float* __restrict__ st2, int n) {
    __shared__ float sW[H1_ * H2_];   // 2 KB
    int tid = threadIdx.x;
    for (int i = tid; i < H1_ * H2_; i += 256) sW[i] = W2[i];
    __syncthreads();
    int idx = blockIdx.x * blockDim.x + tid;
    if (idx >= n) return;
    int node = idx / H2_;
    int f    = idx - node * H2_;
    const float* hr = &h[node * H1_];
    float acc = 0.0f;
#pragma unroll
    for (int k = 0; k < H1_; ++k) acc = fmaf(hr[k], sW[k * H2_ + f], acc);
    st2[idx] = acc * dinv[node];
}

// ============ aggregate layer 2 (fp32, F=10) ============

template <int F, bool RELU>
__global__ __launch_bounds__(256) void csr_aggregate(const float* __restrict__ st,
                                                     const int* __restrict__ rowptr,
                                                     const int* __restrict__ ecol,
                                                     const float* __restrict__ dinv,
                                                     const float* __restrict__ b,
                                                     float* __restrict__ out, int N) {
    int idx = blockIdx.x * blockDim.x + threadIdx.x;
    if (idx >= N * F) return;
    int d = idx / F;
    int f = idx - d * F;
    float acc = st[idx];            // self-loop term
    int j = rowptr[d], end = rowptr[d + 1];
    for (; j + 3 < end; j += 4) {
        int s0 = ecol[j], s1 = ecol[j + 1], s2 = ecol[j + 2], s3 = ecol[j + 3];
        float a0 = st[s0 * F + f], a1 = st[s1 * F + f];
        float a2 = st[s2 * F + f], a3 = st[s3 * F + f];
        acc += (a0 + a1) + (a2 + a3);
    }
    for (; j < end; ++j) acc += st[ecol[j] * F + f];
    float v = fmaf(dinv[d], acc, b[f]);
    out[idx] = RELU ? fmaxf(v, 0.0f) : v;
}

// ================= decode =================

__global__ void decode_kernel(const float* __restrict__ z, const int* __restrict__ pos,
                              const int* __restrict__ neg, float* __restrict__ logits, int EP) {
    int i = blockIdx.x * blockDim.x + threadIdx.x;
    if (i >= 2 * EP) return;
    int a, b;
    if (i < EP) { a = pos[i]; b = pos[EP + i]; }
    else        { int j = i - EP; a = neg[j]; b = neg[EP + j]; }
    const float* za = &z[a * H2_];
    const float* zb = &z[b * H2_];
    float acc = 0.0f;
#pragma unroll
    for (int f = 0; f < H2_; ++f) acc = fmaf(za[f], zb[f], acc);
    logits[i] = acc;
}

// ================= launch =================

extern "C" void kernel_launch(void* const* d_in, const int* in_sizes, int n_in,
                              void* d_out, int out_size, void* d_ws, size_t ws_size,
                              hipStream_t stream) {
    const float* x   = (const float*)d_in[0];
    const float* W1  = (const float*)d_in[1];
    const float* b1  = (const float*)d_in[2];
    const float* W2  = (const float*)d_in[3];
    const float* b2  = (const float*)d_in[4];
    const int* train = (const int*)d_in[5];
    const int* pos   = (const int*)d_in[6];
    const int* neg   = (const int*)d_in[7];

    const int N  = in_sizes[0] / FIN;       // 100000
    const int E  = in_sizes[5] / 2;         // 3200000
    const int EP = in_sizes[6] / 2;         // 1600000

    const int* tsrc = train;
    const int* tdst = train + E;

    // ---- workspace layout (~33.6 MB peak) ----
    size_t off = 0;
    int* rowptr   = (int*)d_ws;              off += (size_t)N + 1;
    int* bcnt     = (int*)d_ws + off;        off += NB_MAX;
    int* bbase    = (int*)d_ws + off;        off += NB_MAX + 1;
    int* bcursor  = (int*)d_ws + off;        off += NB_MAX;
    float* dinv   = (float*)d_ws + off;      off += N;
    off = (off + 3) & ~(size_t)3;            // 16B-align
    float* regA   = (float*)d_ws + off;      off += (size_t)32 * N;
    float* regB   = (float*)d_ws + off;
    unsigned short* st1p = (unsigned short*)regA;   // 64N ushorts = 128N bytes
    float* st2    = regA;                            // overlays st1p after agg1
    float* out2   = regA + (size_t)10 * N;           // z
    float* out1   = regB;                            // h after relu, 50N floats
    int* pairbuf  = (int*)regB;                      // E = 32N ints, dead before agg1
    int* ecol     = (int*)d_out;                     // E ints; dead before decode
    float* logits = (float*)d_out;

    const int NB2 = (N + BKT_W - 1) >> BKT_SHIFT;   // 782 <= NB_MAX
    const int P1B = (E + P1_CHUNK - 1) / P1_CHUNK;  // 391

    // ---- CSR build ----
    hipMemsetAsync(bcnt, 0, NB_MAX * sizeof(int), stream);
    bucket_count<<<P1B, 256, 0, stream>>>(tdst, bcnt, E);
    bucket_scan<<<1, 256, 0, stream>>>(bcnt, bbase, bcursor, NB2, E);
    partition_pass1<<<P1B, 256, 0, stream>>>(tsrc, tdst, bcursor, pairbuf, E);
    bucket_fill_scan<<<NB2, 256, 0, stream>>>(pairbuf, bbase, rowptr, dinv, ecol, N, E);

    // ---- layer 1 ----
    gemm1_kernel<<<(N + G1_NODES - 1) / G1_NODES, 256, 0, stream>>>(x, W1, dinv, st1p, N);
    csr_aggregate1<<<(N * F2 + 255) / 256, 256, 0, stream>>>(
        st1p, rowptr, ecol, dinv, b1, out1, N);

    // ---- layer 2 ----
    gemm2_kernel<<<(N * H2_ + 255) / 256, 256, 0, stream>>>(out1, W2, dinv, st2, N * H2_);
    csr_aggregate<H2_, false><<<(N * H2_ + 255) / 256, 256, 0, stream>>>(
        st2, rowptr, ecol, dinv, b2, out2, N);

    // ---- decode ----
    decode_kernel<<<(2 * EP + 255) / 256, 256, 0, stream>>>(out2, pos, neg, logits, EP);
}

// Round 9
// 451.724 us; speedup vs baseline: 3.2738x; 1.0546x over previous
//
#include <hip/hip_runtime.h>

#define FIN 128
#define H1_ 50
#define H2_ 10

#define BKT_SHIFT 7
#define BKT_W 128              // nodes per fine bucket
#define NB_MAX 800             // >= ceil(100000/128) = 782
#define SB_SHIFT 11
#define SB_W 2048              // nodes per super-bucket (= 16 fine buckets)
#define NSB_MAX 64             // >= ceil(100000/2048) = 49
#define P1_CHUNK 8192          // edges per block, SB partition
#define P1F_CHUNK 4096         // edges per block, fine partition

// ---------------- bf16 helpers (RNE) ----------------

__device__ inline float bf2f(unsigned int u16) {
    union { unsigned int i; float f; } c; c.i = u16 << 16; return c.f;
}
__device__ inline unsigned short f2bf(float f) {
    union { float f; unsigned int i; } c; c.f = f;
    unsigned int x = c.i;
    return (unsigned short)((x + 0x7FFFu + ((x >> 16) & 1u)) >> 16);
}

// ================= fine-bucket histogram (LDS-staged) =================

__global__ __launch_bounds__(256) void bucket_count(const int* __restrict__ dst,
                                                    int* __restrict__ bcnt, int E) {
    __shared__ int lh[NB_MAX];
    int tid = threadIdx.x;
    for (int i = tid; i < NB_MAX; i += 256) lh[i] = 0;
    __syncthreads();
    int lo = blockIdx.x * P1_CHUNK;
    int hi = min(lo + P1_CHUNK, E);
    for (int e = lo + tid; e < hi; e += 256)
        atomicAdd(&lh[dst[e] >> BKT_SHIFT], 1);
    __syncthreads();
    for (int b = tid; b < NB_MAX; b += 256) {
        int c = lh[b];
        if (c) atomicAdd(&bcnt[b], c);
    }
}

// single block: scan fine counts -> bbase/bcursor; derive SB bases/cursors
__global__ __launch_bounds__(256) void bucket_scan(const int* __restrict__ bcnt,
                                                   int* __restrict__ bbase,
                                                   int* __restrict__ bcursor,
                                                   int* __restrict__ sbbase,
                                                   int* __restrict__ sbcursor,
                                                   int nb2, int nsb, int E) {
    __shared__ int s[256];
    int t = threadIdx.x;
    int base = t * 4;
    int v0 = (base + 0 < nb2) ? bcnt[base + 0] : 0;
    int v1 = (base + 1 < nb2) ? bcnt[base + 1] : 0;
    int v2 = (base + 2 < nb2) ? bcnt[base + 2] : 0;
    int v3 = (base + 3 < nb2) ? bcnt[base + 3] : 0;
    int tsum = v0 + v1 + v2 + v3;
    s[t] = tsum;
    __syncthreads();
    for (int off = 1; off < 256; off <<= 1) {
        int x = (t >= off) ? s[t - off] : 0;
        __syncthreads();
        s[t] += x;
        __syncthreads();
    }
    int excl = s[t] - tsum;
    if (t == 0) bbase[nb2] = E;
    if (base + 0 < nb2) { bbase[base + 0] = excl; bcursor[base + 0] = excl; }
    excl += v0;
    if (base + 1 < nb2) { bbase[base + 1] = excl; bcursor[base + 1] = excl; }
    excl += v1;
    if (base + 2 < nb2) { bbase[base + 2] = excl; bcursor[base + 2] = excl; }
    excl += v2;
    if (base + 3 < nb2) { bbase[base + 3] = excl; bcursor[base + 3] = excl; }
    __syncthreads();                       // bbase globally visible within block
    if (t < nsb) {
        int v = bbase[t * 16];             // fine buckets nest 16-per-SB
        sbbase[t] = v;
        sbcursor[t] = v;
    }
    if (t == 0) sbbase[nsb] = E;
}

// ======== level 1: partition edges into 49 super-buckets (dense runs ~668 B) =====
// record: src (bits 0..16) | dst-within-SB (bits 17..27)

__global__ __launch_bounds__(256) void partition_sb(const int* __restrict__ src,
                                                    const int* __restrict__ dst,
                                                    int* __restrict__ sbcursor,
                                                    int* __restrict__ pairbuf1, int E) {
    __shared__ int lh[NSB_MAX];
    __shared__ int lb[NSB_MAX];
    int tid = threadIdx.x;
    if (tid < NSB_MAX) lh[tid] = 0;
    __syncthreads();
    int lo = blockIdx.x * P1_CHUNK;
    int hi = min(lo + P1_CHUNK, E);
    for (int e = lo + tid; e < hi; e += 256)
        atomicAdd(&lh[dst[e] >> SB_SHIFT], 1);
    __syncthreads();
    if (tid < NSB_MAX) {
        int c = lh[tid];
        lb[tid] = c ? atomicAdd(&sbcursor[tid], c) : 0;
        lh[tid] = 0;
    }
    __syncthreads();
    for (int e = lo + tid; e < hi; e += 256) {
        int sv = src[e], d = dst[e];
        int b = d >> SB_SHIFT;
        int r = atomicAdd(&lh[b], 1);
        pairbuf1[lb[b] + r] = sv | ((d & (SB_W - 1)) << 17);
    }
}

// ======== level 2: partition each SB into its 16 fine buckets (runs = 1 KB) ======
// in:  src | dstInSB<<17      out: src | dstInFine<<17

__global__ __launch_bounds__(256) void partition_fine(const int* __restrict__ pairbuf1,
                                                      const int* __restrict__ sbbase,
                                                      int* __restrict__ bcursor,
                                                      int* __restrict__ pairbuf2) {
    int sb = blockIdx.y;
    int seg_lo = sbbase[sb], seg_hi = sbbase[sb + 1];
    int lo = seg_lo + blockIdx.x * P1F_CHUNK;
    if (lo >= seg_hi) return;
    int hi = min(lo + P1F_CHUNK, seg_hi);
    __shared__ int lh[16];
    __shared__ int lb[16];
    int tid = threadIdx.x;
    if (tid < 16) lh[tid] = 0;
    __syncthreads();
    for (int j = lo + tid; j < hi; j += 256)
        atomicAdd(&lh[(pairbuf1[j] >> 17) >> BKT_SHIFT], 1);
    __syncthreads();
    if (tid < 16) {
        int c = lh[tid];
        lb[tid] = c ? atomicAdd(&bcursor[sb * 16 + tid], c) : 0;
        lh[tid] = 0;
    }
    __syncthreads();
    for (int j = lo + tid; j < hi; j += 256) {
        int p = pairbuf1[j];
        int din = p >> 17;
        int fb = din >> BKT_SHIFT;
        int r = atomicAdd(&lh[fb], 1);
        pairbuf2[lb[fb] + r] = (p & 0x1FFFF) | ((din & (BKT_W - 1)) << 17);
    }
}

// ========== pass 2: per-bucket count + scan + rowptr/dinv + fill (fused) ==========

__global__ __launch_bounds__(256) void bucket_fill_scan(const int* __restrict__ pairbuf,
                                                        const int* __restrict__ bbase,
                                                        int* __restrict__ rowptr,
                                                        float* __restrict__ dinv,
                                                        int* __restrict__ ecol,
                                                        int N, int E) {
    __shared__ int cnt[BKT_W];
    __shared__ int sc[BKT_W];
    __shared__ int cur[BKT_W];
    int b = blockIdx.x;
    int base_node = b << BKT_SHIFT;
    int nnodes = min(BKT_W, N - base_node);
    int tid = threadIdx.x;
    if (tid < BKT_W) cnt[tid] = 0;
    __syncthreads();
    int lo = bbase[b], hi = bbase[b + 1];
    for (int j = lo + tid; j < hi; j += 256)
        atomicAdd(&cnt[pairbuf[j] >> 17], 1);
    __syncthreads();
    int c = (tid < BKT_W) ? cnt[tid] : 0;
    if (tid < BKT_W) sc[tid] = c;
    __syncthreads();
    for (int off = 1; off < BKT_W; off <<= 1) {
        int xv = (tid >= off && tid < BKT_W) ? sc[tid - off] : 0;
        __syncthreads();
        if (tid < BKT_W) sc[tid] += xv;
        __syncthreads();
    }
    if (tid < nnodes) {
        int rp = lo + sc[tid] - c;           // exclusive prefix within bucket
        rowptr[base_node + tid] = rp;
        cur[tid] = rp;
        dinv[base_node + tid] = rsqrtf(1.0f + (float)c);   // deg incl self-loop
    }
    __syncthreads();
    for (int j = lo + tid; j < hi; j += 256) {
        int p = pairbuf[j];
        int pos = atomicAdd(&cur[p >> 17], 1);
        ecol[pos] = p & 0x1FFFF;
    }
    if (b == (int)gridDim.x - 1 && tid == 0) rowptr[N] = E;
}

// ======== GEMM1 (register-tiled): st1p[N,64] bf16 = (x @ W1) * dinv[node] ========

#define G1_NODES 32
#define SX_PITCH 132
__global__ __launch_bounds__(256) void gemm1_kernel(const float* __restrict__ x,
                                                    const float* __restrict__ W1,
                                                    const float* __restrict__ dinv,
                                                    unsigned short* __restrict__ st1p, int N) {
    __shared__ float sW[FIN * 64];            // 32 KB, [k][f64]
    __shared__ float sX[G1_NODES * SX_PITCH]; // 16.9 KB
    int tid = threadIdx.x;
    int nb = blockIdx.x * G1_NODES;
    for (int i = tid; i < FIN * 64; i += 256) {
        int k = i >> 6, f = i & 63;
        sW[i] = (f < H1_) ? W1[k * H1_ + f] : 0.0f;
    }
    {
        const float4* x4 = (const float4*)(x + (size_t)nb * FIN);
        for (int i = tid; i < G1_NODES * 32; i += 256) {
            int ln = i >> 5, kk = i & 31;
            float4 v = (nb + ln < N) ? x4[(size_t)ln * 32 + kk]
                                     : make_float4(0.f, 0.f, 0.f, 0.f);
            *(float4*)(&sX[ln * SX_PITCH + kk * 4]) = v;
        }
    }
    __syncthreads();
    int ln = tid >> 3;
    int g  = tid & 7;
    int node = nb + ln;
    const float* xr = &sX[ln * SX_PITCH];
    const float* wc = &sW[g * 8];
    float acc[8] = {0, 0, 0, 0, 0, 0, 0, 0};
#pragma unroll 4
    for (int k = 0; k < FIN; ++k) {
        float xv = xr[k];
        const float* w = &wc[k * 64];
#pragma unroll
        for (int j = 0; j < 8; ++j) acc[j] = fmaf(xv, w[j], acc[j]);
    }
    if (node >= N) return;
    float di = dinv[node];
    unsigned short o[8];
#pragma unroll
    for (int j = 0; j < 8; ++j) o[j] = f2bf(acc[j] * di);
    uint4 pk;
    pk.x = (unsigned)o[0] | ((unsigned)o[1] << 16);
    pk.y = (unsigned)o[2] | ((unsigned)o[3] << 16);
    pk.z = (unsigned)o[4] | ((unsigned)o[5] << 16);
    pk.w = (unsigned)o[6] | ((unsigned)o[7] << 16);
    *(uint4*)(st1p + (size_t)node * 64 + g * 8) = pk;
}

// ============ aggregate layer 1: bf16 gather, fp32 accumulate ============

#define F2 25
__global__ __launch_bounds__(256) void csr_aggregate1(const unsigned short* __restrict__ st,
                                                      const int* __restrict__ rowptr,
                                                      const int* __restrict__ ecol,
                                                      const float* __restrict__ dinv,
                                                      const float* __restrict__ b,
                                                      float* __restrict__ out, int N) {
    int idx = blockIdx.x * blockDim.x + threadIdx.x;
    if (idx >= N * F2) return;
    int d  = idx / F2;
    int fp = idx - d * F2;
    int fo = 2 * fp;
    unsigned int self2 = *(const unsigned int*)(st + (size_t)d * 64 + fo);
    float acc0 = bf2f(self2 & 0xFFFFu);
    float acc1 = bf2f(self2 >> 16);
    int j = rowptr[d], end = rowptr[d + 1];
    for (; j + 3 < end; j += 4) {
        int s0 = ecol[j], s1 = ecol[j + 1], s2 = ecol[j + 2], s3 = ecol[j + 3];
        unsigned int v0 = *(const unsigned int*)(st + (size_t)s0 * 64 + fo);
        unsigned int v1 = *(const unsigned int*)(st + (size_t)s1 * 64 + fo);
        unsigned int v2 = *(const unsigned int*)(st + (size_t)s2 * 64 + fo);
        unsigned int v3 = *(const unsigned int*)(st + (size_t)s3 * 64 + fo);
        acc0 += (bf2f(v0 & 0xFFFFu) + bf2f(v1 & 0xFFFFu)) + (bf2f(v2 & 0xFFFFu) + bf2f(v3 & 0xFFFFu));
        acc1 += (bf2f(v0 >> 16) + bf2f(v1 >> 16)) + (bf2f(v2 >> 16) + bf2f(v3 >> 16));
    }
    for (; j < end; ++j) {
        unsigned int v = *(const unsigned int*)(st + (size_t)ecol[j] * 64 + fo);
        acc0 += bf2f(v & 0xFFFFu);
        acc1 += bf2f(v >> 16);
    }
    float vd = dinv[d];
    float r0 = fmaxf(fmaf(vd, acc0, b[fo]),     0.0f);
    float r1 = fmaxf(fmaf(vd, acc1, b[fo + 1]), 0.0f);
    *(float2*)(out + (size_t)d * H1_ + fo) = make_float2(r0, r1);
}

// ================= GEMM2: st2[N,10] = (h @ W2) * dinv[node] =================

__global__ __launch_bounds__(256) void gemm2_kernel(const float* __restrict__ h,
                                                    const float* __restrict__ W2,
                                                    const float* __restrict__ dinv,
                                                    float* __restrict__ st2, int n) {
    __shared__ float sW[H1_ * H2_];   // 2 KB
    int tid = threadIdx.x;
    for (int i = tid; i < H1_ * H2_; i += 256) sW[i] = W2[i];
    __syncthreads();
    int idx = blockIdx.x * blockDim.x + tid;
    if (idx >= n) return;
    int node = idx / H2_;
    int f    = idx - node * H2_;
    const float* hr = &h[node * H1_];
    float acc = 0.0f;
#pragma unroll
    for (int k = 0; k < H1_; ++k) acc = fmaf(hr[k], sW[k * H2_ + f], acc);
    st2[idx] = acc * dinv[node];
}

// ============ aggregate layer 2 (fp32, F=10) ============

template <int F, bool RELU>
__global__ __launch_bounds__(256) void csr_aggregate(const float* __restrict__ st,
                                                     const int* __restrict__ rowptr,
                                                     const int* __restrict__ ecol,
                                                     const float* __restrict__ dinv,
                                                     const float* __restrict__ b,
                                                     float* __restrict__ out, int N) {
    int idx = blockIdx.x * blockDim.x + threadIdx.x;
    if (idx >= N * F) return;
    int d = idx / F;
    int f = idx - d * F;
    float acc = st[idx];            // self-loop term
    int j = rowptr[d], end = rowptr[d + 1];
    for (; j + 3 < end; j += 4) {
        int s0 = ecol[j], s1 = ecol[j + 1], s2 = ecol[j + 2], s3 = ecol[j + 3];
        float a0 = st[s0 * F + f], a1 = st[s1 * F + f];
        float a2 = st[s2 * F + f], a3 = st[s3 * F + f];
        acc += (a0 + a1) + (a2 + a3);
    }
    for (; j < end; ++j) acc += st[ecol[j] * F + f];
    float v = fmaf(dinv[d], acc, b[f]);
    out[idx] = RELU ? fmaxf(v, 0.0f) : v;
}

// ================= decode =================

__global__ void decode_kernel(const float* __restrict__ z, const int* __restrict__ pos,
                              const int* __restrict__ neg, float* __restrict__ logits, int EP) {
    int i = blockIdx.x * blockDim.x + threadIdx.x;
    if (i >= 2 * EP) return;
    int a, b;
    if (i < EP) { a = pos[i]; b = pos[EP + i]; }
    else        { int j = i - EP; a = neg[j]; b = neg[EP + j]; }
    const float* za = &z[a * H2_];
    const float* zb = &z[b * H2_];
    float acc = 0.0f;
#pragma unroll
    for (int f = 0; f < H2_; ++f) acc = fmaf(za[f], zb[f], acc);
    logits[i] = acc;
}

// ================= launch =================

extern "C" void kernel_launch(void* const* d_in, const int* in_sizes, int n_in,
                              void* d_out, int out_size, void* d_ws, size_t ws_size,
                              hipStream_t stream) {
    const float* x   = (const float*)d_in[0];
    const float* W1  = (const float*)d_in[1];
    const float* b1  = (const float*)d_in[2];
    const float* W2  = (const float*)d_in[3];
    const float* b2  = (const float*)d_in[4];
    const int* train = (const int*)d_in[5];
    const int* pos   = (const int*)d_in[6];
    const int* neg   = (const int*)d_in[7];

    const int N  = in_sizes[0] / FIN;       // 100000
    const int E  = in_sizes[5] / 2;         // 3200000
    const int EP = in_sizes[6] / 2;         // 1600000

    const int* tsrc = train;
    const int* tdst = train + E;

    // ---- workspace layout (~33.7 MB peak) ----
    // ints: rowptr[N+1] | bcnt[NB_MAX] | bbase[NB_MAX+1] | bcursor[NB_MAX] | sbbase[NSB_MAX+1] | sbcursor[NSB_MAX]
    // floats: dinv[N]
    // regA = 32N floats: pairbuf1 int[E=32N] -> st1p bf16[N*64] -> st2[10N]|out2[10N]
    // regB = 50N floats: pairbuf2 int[E] -> out1[50N]
    size_t off = 0;
    int* rowptr   = (int*)d_ws;              off += (size_t)N + 1;
    int* bcnt     = (int*)d_ws + off;        off += NB_MAX;
    int* bbase    = (int*)d_ws + off;        off += NB_MAX + 1;
    int* bcursor  = (int*)d_ws + off;        off += NB_MAX;
    int* sbbase   = (int*)d_ws + off;        off += NSB_MAX + 1;
    int* sbcursor = (int*)d_ws + off;        off += NSB_MAX;
    float* dinv   = (float*)d_ws + off;      off += N;
    off = (off + 3) & ~(size_t)3;            // 16B-align
    float* regA   = (float*)d_ws + off;      off += (size_t)32 * N;
    float* regB   = (float*)d_ws + off;
    int* pairbuf1 = (int*)regA;                      // E ints, dead before gemm1
    unsigned short* st1p = (unsigned short*)regA;    // 64N ushorts = 128N bytes
    float* st2    = regA;                            // overlays st1p after agg1
    float* out2   = regA + (size_t)10 * N;           // z
    int* pairbuf2 = (int*)regB;                      // E ints, dead before agg1
    float* out1   = regB;                            // h after relu, 50N floats
    int* ecol     = (int*)d_out;                     // E ints; dead before decode
    float* logits = (float*)d_out;

    const int NB2 = (N + BKT_W - 1) >> BKT_SHIFT;   // 782 <= NB_MAX
    const int NSB = (N + SB_W - 1) >> SB_SHIFT;     // 49 <= NSB_MAX
    const int P1B = (E + P1_CHUNK - 1) / P1_CHUNK;  // 391
    int p1f_blocks = (2 * (E / NSB) + P1F_CHUNK - 1) / P1F_CHUNK + 1;  // 2x margin

    // ---- CSR build (two-level partition, all writes line-dense) ----
    hipMemsetAsync(bcnt, 0, NB_MAX * sizeof(int), stream);
    bucket_count<<<P1B, 256, 0, stream>>>(tdst, bcnt, E);
    bucket_scan<<<1, 256, 0, stream>>>(bcnt, bbase, bcursor, sbbase, sbcursor, NB2, NSB, E);
    partition_sb<<<P1B, 256, 0, stream>>>(tsrc, tdst, sbcursor, pairbuf1, E);
    partition_fine<<<dim3(p1f_blocks, NSB), 256, 0, stream>>>(pairbuf1, sbbase, bcursor, pairbuf2);
    bucket_fill_scan<<<NB2, 256, 0, stream>>>(pairbuf2, bbase, rowptr, dinv, ecol, N, E);

    // ---- layer 1 ----
    gemm1_kernel<<<(N + G1_NODES - 1) / G1_NODES, 256, 0, stream>>>(x, W1, dinv, st1p, N);
    csr_aggregate1<<<(N * F2 + 255) / 256, 256, 0, stream>>>(
        st1p, rowptr, ecol, dinv, b1, out1, N);

    // ---- layer 2 ----
    gemm2_kernel<<<(N * H2_ + 255) / 256, 256, 0, stream>>>(out1, W2, dinv, st2, N * H2_);
    csr_aggregate<H2_, false><<<(N * H2_ + 255) / 256, 256, 0, stream>>>(
        st2, rowptr, ecol, dinv, b2, out2, N);

    // ---- decode ----
    decode_kernel<<<(2 * EP + 255) / 256, 256, 0, stream>>>(out2, pos, neg, logits, EP);
}

// Round 10
// 449.101 us; speedup vs baseline: 3.2929x; 1.0058x over previous
//
#include <hip/hip_runtime.h>

#define FIN 128
#define H1_ 50
#define H2_ 10

#define BKT_SHIFT 7
#define BKT_W 128              // nodes per fine bucket
#define NB_MAX 800             // >= ceil(100000/128) = 782
#define SB_SHIFT 11
#define SB_W 2048              // nodes per super-bucket (= 16 fine buckets)
#define NSB_MAX 64             // >= ceil(100000/2048) = 49
#define P1_CHUNK 8192          // edges per block, SB partition
#define P1F_CHUNK 4096         // edges per block, fine partition

// ---------------- bf16 helpers (RNE) ----------------

__device__ inline float bf2f(unsigned int u16) {
    union { unsigned int i; float f; } c; c.i = u16 << 16; return c.f;
}
__device__ inline unsigned short f2bf(float f) {
    union { float f; unsigned int i; } c; c.f = f;
    unsigned int x = c.i;
    return (unsigned short)((x + 0x7FFFu + ((x >> 16) & 1u)) >> 16);
}

// ================= fine-bucket histogram (LDS-staged) =================

__global__ __launch_bounds__(256) void bucket_count(const int* __restrict__ dst,
                                                    int* __restrict__ bcnt, int E) {
    __shared__ int lh[NB_MAX];
    int tid = threadIdx.x;
    for (int i = tid; i < NB_MAX; i += 256) lh[i] = 0;
    __syncthreads();
    int lo = blockIdx.x * P1_CHUNK;
    int hi = min(lo + P1_CHUNK, E);
    for (int e = lo + tid; e < hi; e += 256)
        atomicAdd(&lh[dst[e] >> BKT_SHIFT], 1);
    __syncthreads();
    for (int b = tid; b < NB_MAX; b += 256) {
        int c = lh[b];
        if (c) atomicAdd(&bcnt[b], c);
    }
}

// single block: scan fine counts -> bbase/bcursor; derive SB bases/cursors
__global__ __launch_bounds__(256) void bucket_scan(const int* __restrict__ bcnt,
                                                   int* __restrict__ bbase,
                                                   int* __restrict__ bcursor,
                                                   int* __restrict__ sbbase,
                                                   int* __restrict__ sbcursor,
                                                   int nb2, int nsb, int E) {
    __shared__ int s[256];
    int t = threadIdx.x;
    int base = t * 4;
    int v0 = (base + 0 < nb2) ? bcnt[base + 0] : 0;
    int v1 = (base + 1 < nb2) ? bcnt[base + 1] : 0;
    int v2 = (base + 2 < nb2) ? bcnt[base + 2] : 0;
    int v3 = (base + 3 < nb2) ? bcnt[base + 3] : 0;
    int tsum = v0 + v1 + v2 + v3;
    s[t] = tsum;
    __syncthreads();
    for (int off = 1; off < 256; off <<= 1) {
        int x = (t >= off) ? s[t - off] : 0;
        __syncthreads();
        s[t] += x;
        __syncthreads();
    }
    int excl = s[t] - tsum;
    if (t == 0) bbase[nb2] = E;
    if (base + 0 < nb2) { bbase[base + 0] = excl; bcursor[base + 0] = excl; }
    excl += v0;
    if (base + 1 < nb2) { bbase[base + 1] = excl; bcursor[base + 1] = excl; }
    excl += v1;
    if (base + 2 < nb2) { bbase[base + 2] = excl; bcursor[base + 2] = excl; }
    excl += v2;
    if (base + 3 < nb2) { bbase[base + 3] = excl; bcursor[base + 3] = excl; }
    __syncthreads();
    if (t < nsb) {
        int v = bbase[t * 16];             // fine buckets nest 16-per-SB
        sbbase[t] = v;
        sbcursor[t] = v;
    }
    if (t == 0) sbbase[nsb] = E;
}

// ======== level 1: partition edges into 49 super-buckets =====

__global__ __launch_bounds__(256) void partition_sb(const int* __restrict__ src,
                                                    const int* __restrict__ dst,
                                                    int* __restrict__ sbcursor,
                                                    int* __restrict__ pairbuf1, int E) {
    __shared__ int lh[NSB_MAX];
    __shared__ int lb[NSB_MAX];
    int tid = threadIdx.x;
    if (tid < NSB_MAX) lh[tid] = 0;
    __syncthreads();
    int lo = blockIdx.x * P1_CHUNK;
    int hi = min(lo + P1_CHUNK, E);
    for (int e = lo + tid; e < hi; e += 256)
        atomicAdd(&lh[dst[e] >> SB_SHIFT], 1);
    __syncthreads();
    if (tid < NSB_MAX) {
        int c = lh[tid];
        lb[tid] = c ? atomicAdd(&sbcursor[tid], c) : 0;
        lh[tid] = 0;
    }
    __syncthreads();
    for (int e = lo + tid; e < hi; e += 256) {
        int sv = src[e], d = dst[e];
        int b = d >> SB_SHIFT;
        int r = atomicAdd(&lh[b], 1);
        pairbuf1[lb[b] + r] = sv | ((d & (SB_W - 1)) << 17);
    }
}

// ======== level 2: partition each SB into its 16 fine buckets ======

__global__ __launch_bounds__(256) void partition_fine(const int* __restrict__ pairbuf1,
                                                      const int* __restrict__ sbbase,
                                                      int* __restrict__ bcursor,
                                                      int* __restrict__ pairbuf2) {
    int sb = blockIdx.y;
    int seg_lo = sbbase[sb], seg_hi = sbbase[sb + 1];
    int lo = seg_lo + blockIdx.x * P1F_CHUNK;
    if (lo >= seg_hi) return;
    int hi = min(lo + P1F_CHUNK, seg_hi);
    __shared__ int lh[16];
    __shared__ int lb[16];
    int tid = threadIdx.x;
    if (tid < 16) lh[tid] = 0;
    __syncthreads();
    for (int j = lo + tid; j < hi; j += 256)
        atomicAdd(&lh[(pairbuf1[j] >> 17) >> BKT_SHIFT], 1);
    __syncthreads();
    if (tid < 16) {
        int c = lh[tid];
        lb[tid] = c ? atomicAdd(&bcursor[sb * 16 + tid], c) : 0;
        lh[tid] = 0;
    }
    __syncthreads();
    for (int j = lo + tid; j < hi; j += 256) {
        int p = pairbuf1[j];
        int din = p >> 17;
        int fb = din >> BKT_SHIFT;
        int r = atomicAdd(&lh[fb], 1);
        pairbuf2[lb[fb] + r] = (p & 0x1FFFF) | ((din & (BKT_W - 1)) << 17);
    }
}

// ========== pass 2: per-bucket count + scan + rowptr/dinv + fill (fused) ==========

__global__ __launch_bounds__(256) void bucket_fill_scan(const int* __restrict__ pairbuf,
                                                        const int* __restrict__ bbase,
                                                        int* __restrict__ rowptr,
                                                        float* __restrict__ dinv,
                                                        int* __restrict__ ecol,
                                                        int N, int E) {
    __shared__ int cnt[BKT_W];
    __shared__ int sc[BKT_W];
    __shared__ int cur[BKT_W];
    int b = blockIdx.x;
    int base_node = b << BKT_SHIFT;
    int nnodes = min(BKT_W, N - base_node);
    int tid = threadIdx.x;
    if (tid < BKT_W) cnt[tid] = 0;
    __syncthreads();
    int lo = bbase[b], hi = bbase[b + 1];
    for (int j = lo + tid; j < hi; j += 256)
        atomicAdd(&cnt[pairbuf[j] >> 17], 1);
    __syncthreads();
    int c = (tid < BKT_W) ? cnt[tid] : 0;
    if (tid < BKT_W) sc[tid] = c;
    __syncthreads();
    for (int off = 1; off < BKT_W; off <<= 1) {
        int xv = (tid >= off && tid < BKT_W) ? sc[tid - off] : 0;
        __syncthreads();
        if (tid < BKT_W) sc[tid] += xv;
        __syncthreads();
    }
    if (tid < nnodes) {
        int rp = lo + sc[tid] - c;           // exclusive prefix within bucket
        rowptr[base_node + tid] = rp;
        cur[tid] = rp;
        dinv[base_node + tid] = rsqrtf(1.0f + (float)c);   // deg incl self-loop
    }
    __syncthreads();
    for (int j = lo + tid; j < hi; j += 256) {
        int p = pairbuf[j];
        int pos = atomicAdd(&cur[p >> 17], 1);
        ecol[pos] = p & 0x1FFFF;
    }
    if (b == (int)gridDim.x - 1 && tid == 0) rowptr[N] = E;
}

// ======== GEMM1 v3 (node-pair register-blocked): st1p[N,64] bf16 ========
// 64 nodes/block; thread = (node-pair, 8-feat group): 16 accumulators.
// Per k-step: 2x ds_read_b128 (W, reused for 2 nodes) + 2x ds_read_b32 (x).

#define G1_NODES 64
#define SX_PITCH 132
__global__ __launch_bounds__(256) void gemm1_kernel(const float* __restrict__ x,
                                                    const float* __restrict__ W1,
                                                    const float* __restrict__ dinv,
                                                    unsigned short* __restrict__ st1p, int N) {
    __shared__ float sW[FIN * 64];            // 32 KB, [k][f64]
    __shared__ float sX[G1_NODES * SX_PITCH]; // 33.8 KB
    int tid = threadIdx.x;
    int nb = blockIdx.x * G1_NODES;
    for (int i = tid; i < FIN * 64; i += 256) {
        int k = i >> 6, f = i & 63;
        sW[i] = (f < H1_) ? W1[k * H1_ + f] : 0.0f;
    }
    {
        const float4* x4 = (const float4*)(x + (size_t)nb * FIN);
        for (int i = tid; i < G1_NODES * 32; i += 256) {   // 2048 float4 stages
            int ln = i >> 5, kk = i & 31;
            float4 v = (nb + ln < N) ? x4[(size_t)ln * 32 + kk]
                                     : make_float4(0.f, 0.f, 0.f, 0.f);
            *(float4*)(&sX[ln * SX_PITCH + kk * 4]) = v;
        }
    }
    __syncthreads();
    int pr = tid >> 3;        // 0..31 node pair
    int g  = tid & 7;         // 0..7
    int node0 = nb + 2 * pr;
    const float* xr0 = &sX[(2 * pr) * SX_PITCH];
    const float* xr1 = &sX[(2 * pr + 1) * SX_PITCH];
    const float* wc = &sW[g * 8];
    float a0[8] = {0, 0, 0, 0, 0, 0, 0, 0};
    float a1[8] = {0, 0, 0, 0, 0, 0, 0, 0};
#pragma unroll 4
    for (int k = 0; k < FIN; ++k) {
        float xv0 = xr0[k];
        float xv1 = xr1[k];
        const float* w = &wc[k * 64];
#pragma unroll
        for (int j = 0; j < 8; ++j) {
            float wv = w[j];
            a0[j] = fmaf(xv0, wv, a0[j]);
            a1[j] = fmaf(xv1, wv, a1[j]);
        }
    }
    if (node0 < N) {
        float di = dinv[node0];
        unsigned short o[8];
#pragma unroll
        for (int j = 0; j < 8; ++j) o[j] = f2bf(a0[j] * di);
        uint4 pk;
        pk.x = (unsigned)o[0] | ((unsigned)o[1] << 16);
        pk.y = (unsigned)o[2] | ((unsigned)o[3] << 16);
        pk.z = (unsigned)o[4] | ((unsigned)o[5] << 16);
        pk.w = (unsigned)o[6] | ((unsigned)o[7] << 16);
        *(uint4*)(st1p + (size_t)node0 * 64 + g * 8) = pk;
    }
    if (node0 + 1 < N) {
        float di = dinv[node0 + 1];
        unsigned short o[8];
#pragma unroll
        for (int j = 0; j < 8; ++j) o[j] = f2bf(a1[j] * di);
        uint4 pk;
        pk.x = (unsigned)o[0] | ((unsigned)o[1] << 16);
        pk.y = (unsigned)o[2] | ((unsigned)o[3] << 16);
        pk.z = (unsigned)o[4] | ((unsigned)o[5] << 16);
        pk.w = (unsigned)o[6] | ((unsigned)o[7] << 16);
        *(uint4*)(st1p + (size_t)(node0 + 1) * 64 + g * 8) = pk;
    }
}

// ============ aggregate layer 1: bf16 gather, fp32 accumulate ============

#define F2 25
__global__ __launch_bounds__(256) void csr_aggregate1(const unsigned short* __restrict__ st,
                                                      const int* __restrict__ rowptr,
                                                      const int* __restrict__ ecol,
                                                      const float* __restrict__ dinv,
                                                      const float* __restrict__ b,
                                                      float* __restrict__ out, int N) {
    int idx = blockIdx.x * blockDim.x + threadIdx.x;
    if (idx >= N * F2) return;
    int d  = idx / F2;
    int fp = idx - d * F2;
    int fo = 2 * fp;
    unsigned int self2 = *(const unsigned int*)(st + (size_t)d * 64 + fo);
    float acc0 = bf2f(self2 & 0xFFFFu);
    float acc1 = bf2f(self2 >> 16);
    int j = rowptr[d], end = rowptr[d + 1];
    for (; j + 3 < end; j += 4) {
        int s0 = ecol[j], s1 = ecol[j + 1], s2 = ecol[j + 2], s3 = ecol[j + 3];
        unsigned int v0 = *(const unsigned int*)(st + (size_t)s0 * 64 + fo);
        unsigned int v1 = *(const unsigned int*)(st + (size_t)s1 * 64 + fo);
        unsigned int v2 = *(const unsigned int*)(st + (size_t)s2 * 64 + fo);
        unsigned int v3 = *(const unsigned int*)(st + (size_t)s3 * 64 + fo);
        acc0 += (bf2f(v0 & 0xFFFFu) + bf2f(v1 & 0xFFFFu)) + (bf2f(v2 & 0xFFFFu) + bf2f(v3 & 0xFFFFu));
        acc1 += (bf2f(v0 >> 16) + bf2f(v1 >> 16)) + (bf2f(v2 >> 16) + bf2f(v3 >> 16));
    }
    for (; j < end; ++j) {
        unsigned int v = *(const unsigned int*)(st + (size_t)ecol[j] * 64 + fo);
        acc0 += bf2f(v & 0xFFFFu);
        acc1 += bf2f(v >> 16);
    }
    float vd = dinv[d];
    float r0 = fmaxf(fmaf(vd, acc0, b[fo]),     0.0f);
    float r1 = fmaxf(fmaf(vd, acc1, b[fo + 1]), 0.0f);
    *(float2*)(out + (size_t)d * H1_ + fo) = make_float2(r0, r1);
}

// ================= GEMM2: st2[N,10] = (h @ W2) * dinv[node] =================

__global__ __launch_bounds__(256) void gemm2_kernel(const float* __restrict__ h,
                                                    const float* __restrict__ W2,
                                                    const float* __restrict__ dinv,
                                                    float* __restrict__ st2, int n) {
    __shared__ float sW[H1_ * H2_];   // 2 KB
    int tid = threadIdx.x;
    for (int i = tid; i < H1_ * H2_; i += 256) sW[i] = W2[i];
    __syncthreads();
    int idx = blockIdx.x * blockDim.x + tid;
    if (idx >= n) return;
    int node = idx / H2_;
    int f    = idx - node * H2_;
    const float* hr = &h[node * H1_];
    float acc = 0.0f;
#pragma unroll
    for (int k = 0; k < H1_; ++k) acc = fmaf(hr[k], sW[k * H2_ + f], acc);
    st2[idx] = acc * dinv[node];
}

// ============ aggregate layer 2 (fp32, F=10) ============

template <int F, bool RELU>
__global__ __launch_bounds__(256) void csr_aggregate(const float* __restrict__ st,
                                                     const int* __restrict__ rowptr,
                                                     const int* __restrict__ ecol,
                                                     const float* __restrict__ dinv,
                                                     const float* __restrict__ b,
                                                     float* __restrict__ out, int N) {
    int idx = blockIdx.x * blockDim.x + threadIdx.x;
    if (idx >= N * F) return;
    int d = idx / F;
    int f = idx - d * F;
    float acc = st[idx];            // self-loop term
    int j = rowptr[d], end = rowptr[d + 1];
    for (; j + 3 < end; j += 4) {
        int s0 = ecol[j], s1 = ecol[j + 1], s2 = ecol[j + 2], s3 = ecol[j + 3];
        float a0 = st[s0 * F + f], a1 = st[s1 * F + f];
        float a2 = st[s2 * F + f], a3 = st[s3 * F + f];
        acc += (a0 + a1) + (a2 + a3);
    }
    for (; j < end; ++j) acc += st[ecol[j] * F + f];
    float v = fmaf(dinv[d], acc, b[f]);
    out[idx] = RELU ? fmaxf(v, 0.0f) : v;
}

// ================= decode =================

__global__ void decode_kernel(const float* __restrict__ z, const int* __restrict__ pos,
                              const int* __restrict__ neg, float* __restrict__ logits, int EP) {
    int i = blockIdx.x * blockDim.x + threadIdx.x;
    if (i >= 2 * EP) return;
    int a, b;
    if (i < EP) { a = pos[i]; b = pos[EP + i]; }
    else        { int j = i - EP; a = neg[j]; b = neg[EP + j]; }
    const float* za = &z[a * H2_];
    const float* zb = &z[b * H2_];
    float acc = 0.0f;
#pragma unroll
    for (int f = 0; f < H2_; ++f) acc = fmaf(za[f], zb[f], acc);
    logits[i] = acc;
}

// ================= launch =================

extern "C" void kernel_launch(void* const* d_in, const int* in_sizes, int n_in,
                              void* d_out, int out_size, void* d_ws, size_t ws_size,
                              hipStream_t stream) {
    const float* x   = (const float*)d_in[0];
    const float* W1  = (const float*)d_in[1];
    const float* b1  = (const float*)d_in[2];
    const float* W2  = (const float*)d_in[3];
    const float* b2  = (const float*)d_in[4];
    const int* train = (const int*)d_in[5];
    const int* pos   = (const int*)d_in[6];
    const int* neg   = (const int*)d_in[7];

    const int N  = in_sizes[0] / FIN;       // 100000
    const int E  = in_sizes[5] / 2;         // 3200000
    const int EP = in_sizes[6] / 2;         // 1600000

    const int* tsrc = train;
    const int* tdst = train + E;

    // ---- workspace layout (~33.7 MB peak) ----
    size_t off = 0;
    int* rowptr   = (int*)d_ws;              off += (size_t)N + 1;
    int* bcnt     = (int*)d_ws + off;        off += NB_MAX;
    int* bbase    = (int*)d_ws + off;        off += NB_MAX + 1;
    int* bcursor  = (int*)d_ws + off;        off += NB_MAX;
    int* sbbase   = (int*)d_ws + off;        off += NSB_MAX + 1;
    int* sbcursor = (int*)d_ws + off;        off += NSB_MAX;
    float* dinv   = (float*)d_ws + off;      off += N;
    off = (off + 3) & ~(size_t)3;            // 16B-align
    float* regA   = (float*)d_ws + off;      off += (size_t)32 * N;
    float* regB   = (float*)d_ws + off;
    int* pairbuf1 = (int*)regA;                      // E ints, dead before gemm1
    unsigned short* st1p = (unsigned short*)regA;    // 64N ushorts = 128N bytes
    float* st2    = regA;                            // overlays st1p after agg1
    float* out2   = regA + (size_t)10 * N;           // z
    int* pairbuf2 = (int*)regB;                      // E ints, dead before agg1
    float* out1   = regB;                            // h after relu, 50N floats
    int* ecol     = (int*)d_out;                     // E ints; dead before decode
    float* logits = (float*)d_out;

    const int NB2 = (N + BKT_W - 1) >> BKT_SHIFT;   // 782 <= NB_MAX
    const int NSB = (N + SB_W - 1) >> SB_SHIFT;     // 49 <= NSB_MAX
    const int P1B = (E + P1_CHUNK - 1) / P1_CHUNK;  // 391
    int p1f_blocks = (2 * (E / NSB) + P1F_CHUNK - 1) / P1F_CHUNK + 1;  // 2x margin

    // ---- CSR build (two-level partition, all writes line-dense) ----
    hipMemsetAsync(bcnt, 0, NB_MAX * sizeof(int), stream);
    bucket_count<<<P1B, 256, 0, stream>>>(tdst, bcnt, E);
    bucket_scan<<<1, 256, 0, stream>>>(bcnt, bbase, bcursor, sbbase, sbcursor, NB2, NSB, E);
    partition_sb<<<P1B, 256, 0, stream>>>(tsrc, tdst, sbcursor, pairbuf1, E);
    partition_fine<<<dim3(p1f_blocks, NSB), 256, 0, stream>>>(pairbuf1, sbbase, bcursor, pairbuf2);
    bucket_fill_scan<<<NB2, 256, 0, stream>>>(pairbuf2, bbase, rowptr, dinv, ecol, N, E);

    // ---- layer 1 ----
    gemm1_kernel<<<(N + G1_NODES - 1) / G1_NODES, 256, 0, stream>>>(x, W1, dinv, st1p, N);
    csr_aggregate1<<<(N * F2 + 255) / 256, 256, 0, stream>>>(
        st1p, rowptr, ecol, dinv, b1, out1, N);

    // ---- layer 2 ----
    gemm2_kernel<<<(N * H2_ + 255) / 256, 256, 0, stream>>>(out1, W2, dinv, st2, N * H2_);
    csr_aggregate<H2_, false><<<(N * H2_ + 255) / 256, 256, 0, stream>>>(
        st2, rowptr, ecol, dinv, b2, out2, N);

    // ---- decode ----
    decode_kernel<<<(2 * EP + 255) / 256, 256, 0, stream>>>(out2, pos, neg, logits, EP);
}

// Round 11
// 428.844 us; speedup vs baseline: 3.4485x; 1.0472x over previous
//
#include <hip/hip_runtime.h>

#define FIN 128
#define H1_ 50
#define H2_ 10

#define BKT_SHIFT 7
#define BKT_W 128              // nodes per fine bucket
#define NB_MAX 800             // >= ceil(100000/128) = 782
#define SB_SHIFT 11
#define SB_W 2048              // nodes per super-bucket (= 16 fine buckets)
#define NSB_MAX 64             // >= ceil(100000/2048) = 49
#define SB_CAP 81920           // fixed segment capacity (1.25x expected 65536)
#define P1_CHUNK 8192          // edges per block, SB partition
#define P1F_CHUNK 4096         // edges per block, fine partition

// ---------------- bf16 helpers (RNE) ----------------

__device__ inline float bf2f(unsigned int u16) {
    union { unsigned int i; float f; } c; c.i = u16 << 16; return c.f;
}
__device__ inline unsigned short f2bf(float f) {
    union { float f; unsigned int i; } c; c.f = f;
    unsigned int x = c.i;
    return (unsigned short)((x + 0x7FFFu + ((x >> 16) & 1u)) >> 16);
}

// ======== level 1 (fused): SB partition + fine histogram in one pass ========
// record: src (bits 0..16) | dst-within-SB (bits 17..27)
// SB segments are fixed-capacity: base = sb*SB_CAP (no scan dependency).

__global__ __launch_bounds__(256) void partition_sb(const int* __restrict__ src,
                                                    const int* __restrict__ dst,
                                                    int* __restrict__ sbcnt,
                                                    int* __restrict__ bcnt,
                                                    int* __restrict__ pairbuf1,
                                                    int E, int nsb) {
    __shared__ int lh[NB_MAX];     // fine histogram
    __shared__ int lhs[NSB_MAX];   // SB local cursor
    __shared__ int lbs[NSB_MAX];   // SB reserved global base
    int tid = threadIdx.x;
    for (int i = tid; i < NB_MAX; i += 256) lh[i] = 0;
    if (tid < NSB_MAX) lhs[tid] = 0;
    __syncthreads();
    int lo = blockIdx.x * P1_CHUNK;
    int hi = min(lo + P1_CHUNK, E);
    for (int e = lo + tid; e < hi; e += 256)
        atomicAdd(&lh[dst[e] >> BKT_SHIFT], 1);
    __syncthreads();
    if (tid < nsb) {
        int c = 0;
#pragma unroll
        for (int j = 0; j < 16; ++j) {
            int idx = tid * 16 + j;
            c += (idx < NB_MAX) ? lh[idx] : 0;
        }
        lbs[tid] = c ? (tid * SB_CAP + atomicAdd(&sbcnt[tid], c)) : 0;
    }
    for (int i = tid; i < NB_MAX; i += 256) {
        int c = lh[i];
        if (c) atomicAdd(&bcnt[i], c);
    }
    __syncthreads();
    for (int e = lo + tid; e < hi; e += 256) {
        int sv = src[e], d = dst[e];
        int b = d >> SB_SHIFT;
        int r = atomicAdd(&lhs[b], 1);
        pairbuf1[lbs[b] + r] = sv | ((d & (SB_W - 1)) << 17);
    }
}

// single block: scan fine counts -> bbase/bcursor
__global__ __launch_bounds__(256) void bucket_scan(const int* __restrict__ bcnt,
                                                   int* __restrict__ bbase,
                                                   int* __restrict__ bcursor,
                                                   int nb2, int E) {
    __shared__ int s[256];
    int t = threadIdx.x;
    int base = t * 4;
    int v0 = (base + 0 < nb2) ? bcnt[base + 0] : 0;
    int v1 = (base + 1 < nb2) ? bcnt[base + 1] : 0;
    int v2 = (base + 2 < nb2) ? bcnt[base + 2] : 0;
    int v3 = (base + 3 < nb2) ? bcnt[base + 3] : 0;
    int tsum = v0 + v1 + v2 + v3;
    s[t] = tsum;
    __syncthreads();
    for (int off = 1; off < 256; off <<= 1) {
        int x = (t >= off) ? s[t - off] : 0;
        __syncthreads();
        s[t] += x;
        __syncthreads();
    }
    int excl = s[t] - tsum;
    if (t == 0) bbase[nb2] = E;
    if (base + 0 < nb2) { bbase[base + 0] = excl; bcursor[base + 0] = excl; }
    excl += v0;
    if (base + 1 < nb2) { bbase[base + 1] = excl; bcursor[base + 1] = excl; }
    excl += v1;
    if (base + 2 < nb2) { bbase[base + 2] = excl; bcursor[base + 2] = excl; }
    excl += v2;
    if (base + 3 < nb2) { bbase[base + 3] = excl; bcursor[base + 3] = excl; }
}

// ======== level 2: partition each SB segment into its 16 fine buckets ======

__global__ __launch_bounds__(256) void partition_fine(const int* __restrict__ pairbuf1,
                                                      const int* __restrict__ sbcnt,
                                                      int* __restrict__ bcursor,
                                                      int* __restrict__ pairbuf2) {
    int sb = blockIdx.y;
    int cnt = sbcnt[sb];
    int rel = blockIdx.x * P1F_CHUNK;
    if (rel >= cnt) return;
    int lo = sb * SB_CAP + rel;
    int hi = sb * SB_CAP + min(rel + P1F_CHUNK, cnt);
    __shared__ int lh[16];
    __shared__ int lb[16];
    int tid = threadIdx.x;
    if (tid < 16) lh[tid] = 0;
    __syncthreads();
    for (int j = lo + tid; j < hi; j += 256)
        atomicAdd(&lh[(pairbuf1[j] >> 17) >> BKT_SHIFT], 1);
    __syncthreads();
    if (tid < 16) {
        int c = lh[tid];
        lb[tid] = c ? atomicAdd(&bcursor[sb * 16 + tid], c) : 0;
        lh[tid] = 0;
    }
    __syncthreads();
    for (int j = lo + tid; j < hi; j += 256) {
        int p = pairbuf1[j];
        int din = p >> 17;
        int fb = din >> BKT_SHIFT;
        int r = atomicAdd(&lh[fb], 1);
        pairbuf2[lb[fb] + r] = (p & 0x1FFFF) | ((din & (BKT_W - 1)) << 17);
    }
}

// ========== pass 2: per-bucket count + scan + rowptr/dinv + fill (fused) ==========

__global__ __launch_bounds__(256) void bucket_fill_scan(const int* __restrict__ pairbuf,
                                                        const int* __restrict__ bbase,
                                                        int* __restrict__ rowptr,
                                                        float* __restrict__ dinv,
                                                        int* __restrict__ ecol,
                                                        int N, int E) {
    __shared__ int cnt[BKT_W];
    __shared__ int sc[BKT_W];
    __shared__ int cur[BKT_W];
    int b = blockIdx.x;
    int base_node = b << BKT_SHIFT;
    int nnodes = min(BKT_W, N - base_node);
    int tid = threadIdx.x;
    if (tid < BKT_W) cnt[tid] = 0;
    __syncthreads();
    int lo = bbase[b], hi = bbase[b + 1];
    for (int j = lo + tid; j < hi; j += 256)
        atomicAdd(&cnt[pairbuf[j] >> 17], 1);
    __syncthreads();
    int c = (tid < BKT_W) ? cnt[tid] : 0;
    if (tid < BKT_W) sc[tid] = c;
    __syncthreads();
    for (int off = 1; off < BKT_W; off <<= 1) {
        int xv = (tid >= off && tid < BKT_W) ? sc[tid - off] : 0;
        __syncthreads();
        if (tid < BKT_W) sc[tid] += xv;
        __syncthreads();
    }
    if (tid < nnodes) {
        int rp = lo + sc[tid] - c;           // exclusive prefix within bucket
        rowptr[base_node + tid] = rp;
        cur[tid] = rp;
        dinv[base_node + tid] = rsqrtf(1.0f + (float)c);   // deg incl self-loop
    }
    __syncthreads();
    for (int j = lo + tid; j < hi; j += 256) {
        int p = pairbuf[j];
        int pos = atomicAdd(&cur[p >> 17], 1);
        ecol[pos] = p & 0x1FFFF;
    }
    if (b == (int)gridDim.x - 1 && tid == 0) rowptr[N] = E;
}

// ======== GEMM1 v4: 4-node x 8-feat thread tile, W k-sliced ========
// 128 nodes/block, 256 threads: quad q=tid>>3 -> nodes 4q..4q+3, g=tid&7 -> feats 8g..
// Per k-step: 4x ds_read_b32 (x) + 2x ds_read_b128 (W) for 32 FMAs (1.5 B/FMA).

#define G1_NODES 128
#define SX_PITCH 132
#define KCHUNK 32
__global__ __launch_bounds__(256) void gemm1_kernel(const float* __restrict__ x,
                                                    const float* __restrict__ W1,
                                                    const float* __restrict__ dinv,
                                                    unsigned short* __restrict__ st1p, int N) {
    __shared__ float sX[G1_NODES * SX_PITCH]; // 67.6 KB
    __shared__ float sW[KCHUNK * 64];         // 8 KB per k-chunk
    int tid = threadIdx.x;
    int nb = blockIdx.x * G1_NODES;
    {
        const float4* x4 = (const float4*)(x + (size_t)nb * FIN);
        for (int i = tid; i < G1_NODES * 32; i += 256) {   // 4096 float4 stages
            int ln = i >> 5, kk = i & 31;
            float4 v = (nb + ln < N) ? x4[(size_t)ln * 32 + kk]
                                     : make_float4(0.f, 0.f, 0.f, 0.f);
            *(float4*)(&sX[ln * SX_PITCH + kk * 4]) = v;
        }
    }
    int q = tid >> 3;         // 0..31
    int g = tid & 7;          // 0..7
    const float* xr0 = &sX[(4 * q + 0) * SX_PITCH];
    const float* xr1 = &sX[(4 * q + 1) * SX_PITCH];
    const float* xr2 = &sX[(4 * q + 2) * SX_PITCH];
    const float* xr3 = &sX[(4 * q + 3) * SX_PITCH];
    float acc[4][8];
#pragma unroll
    for (int i = 0; i < 4; ++i)
#pragma unroll
        for (int j = 0; j < 8; ++j) acc[i][j] = 0.0f;

    for (int kc = 0; kc < FIN / KCHUNK; ++kc) {
        __syncthreads();     // protect sW from previous iteration's readers
        for (int i = tid; i < KCHUNK * 64; i += 256) {
            int k = i >> 6, f = i & 63;
            sW[i] = (f < H1_) ? W1[(kc * KCHUNK + k) * H1_ + f] : 0.0f;
        }
        __syncthreads();
        int kb = kc * KCHUNK;
#pragma unroll 4
        for (int k = 0; k < KCHUNK; ++k) {
            float xv0 = xr0[kb + k];
            float xv1 = xr1[kb + k];
            float xv2 = xr2[kb + k];
            float xv3 = xr3[kb + k];
            const float* w = &sW[k * 64 + g * 8];
#pragma unroll
            for (int j = 0; j < 8; ++j) {
                float wv = w[j];
                acc[0][j] = fmaf(xv0, wv, acc[0][j]);
                acc[1][j] = fmaf(xv1, wv, acc[1][j]);
                acc[2][j] = fmaf(xv2, wv, acc[2][j]);
                acc[3][j] = fmaf(xv3, wv, acc[3][j]);
            }
        }
    }
#pragma unroll
    for (int i = 0; i < 4; ++i) {
        int node = nb + 4 * q + i;
        if (node >= N) continue;
        float di = dinv[node];
        unsigned short o[8];
#pragma unroll
        for (int j = 0; j < 8; ++j) o[j] = f2bf(acc[i][j] * di);
        uint4 pk;
        pk.x = (unsigned)o[0] | ((unsigned)o[1] << 16);
        pk.y = (unsigned)o[2] | ((unsigned)o[3] << 16);
        pk.z = (unsigned)o[4] | ((unsigned)o[5] << 16);
        pk.w = (unsigned)o[6] | ((unsigned)o[7] << 16);
        *(uint4*)(st1p + (size_t)node * 64 + g * 8) = pk;
    }
}

// ============ aggregate layer 1: bf16 gather, fp32 accumulate ============

#define F2 25
__global__ __launch_bounds__(256) void csr_aggregate1(const unsigned short* __restrict__ st,
                                                      const int* __restrict__ rowptr,
                                                      const int* __restrict__ ecol,
                                                      const float* __restrict__ dinv,
                                                      const float* __restrict__ b,
                                                      float* __restrict__ out, int N) {
    int idx = blockIdx.x * blockDim.x + threadIdx.x;
    if (idx >= N * F2) return;
    int d  = idx / F2;
    int fp = idx - d * F2;
    int fo = 2 * fp;
    unsigned int self2 = *(const unsigned int*)(st + (size_t)d * 64 + fo);
    float acc0 = bf2f(self2 & 0xFFFFu);
    float acc1 = bf2f(self2 >> 16);
    int j = rowptr[d], end = rowptr[d + 1];
    for (; j + 3 < end; j += 4) {
        int s0 = ecol[j], s1 = ecol[j + 1], s2 = ecol[j + 2], s3 = ecol[j + 3];
        unsigned int v0 = *(const unsigned int*)(st + (size_t)s0 * 64 + fo);
        unsigned int v1 = *(const unsigned int*)(st + (size_t)s1 * 64 + fo);
        unsigned int v2 = *(const unsigned int*)(st + (size_t)s2 * 64 + fo);
        unsigned int v3 = *(const unsigned int*)(st + (size_t)s3 * 64 + fo);
        acc0 += (bf2f(v0 & 0xFFFFu) + bf2f(v1 & 0xFFFFu)) + (bf2f(v2 & 0xFFFFu) + bf2f(v3 & 0xFFFFu));
        acc1 += (bf2f(v0 >> 16) + bf2f(v1 >> 16)) + (bf2f(v2 >> 16) + bf2f(v3 >> 16));
    }
    for (; j < end; ++j) {
        unsigned int v = *(const unsigned int*)(st + (size_t)ecol[j] * 64 + fo);
        acc0 += bf2f(v & 0xFFFFu);
        acc1 += bf2f(v >> 16);
    }
    float vd = dinv[d];
    float r0 = fmaxf(fmaf(vd, acc0, b[fo]),     0.0f);
    float r1 = fmaxf(fmaf(vd, acc1, b[fo + 1]), 0.0f);
    *(float2*)(out + (size_t)d * H1_ + fo) = make_float2(r0, r1);
}

// ================= GEMM2: st2[N,10] = (h @ W2) * dinv[node] =================

__global__ __launch_bounds__(256) void gemm2_kernel(const float* __restrict__ h,
                                                    const float* __restrict__ W2,
                                                    const float* __restrict__ dinv,
                                                    float* __restrict__ st2, int n) {
    __shared__ float sW[H1_ * H2_];   // 2 KB
    int tid = threadIdx.x;
    for (int i = tid; i < H1_ * H2_; i += 256) sW[i] = W2[i];
    __syncthreads();
    int idx = blockIdx.x * blockDim.x + tid;
    if (idx >= n) return;
    int node = idx / H2_;
    int f    = idx - node * H2_;
    const float* hr = &h[node * H1_];
    float acc = 0.0f;
#pragma unroll
    for (int k = 0; k < H1_; ++k) acc = fmaf(hr[k], sW[k * H2_ + f], acc);
    st2[idx] = acc * dinv[node];
}

// ============ aggregate layer 2 (fp32, F=10) ============

template <int F, bool RELU>
__global__ __launch_bounds__(256) void csr_aggregate(const float* __restrict__ st,
                                                     const int* __restrict__ rowptr,
                                                     const int* __restrict__ ecol,
                                                     const float* __restrict__ dinv,
                                                     const float* __restrict__ b,
                                                     float* __restrict__ out, int N) {
    int idx = blockIdx.x * blockDim.x + threadIdx.x;
    if (idx >= N * F) return;
    int d = idx / F;
    int f = idx - d * F;
    float acc = st[idx];            // self-loop term
    int j = rowptr[d], end = rowptr[d + 1];
    for (; j + 3 < end; j += 4) {
        int s0 = ecol[j], s1 = ecol[j + 1], s2 = ecol[j + 2], s3 = ecol[j + 3];
        float a0 = st[s0 * F + f], a1 = st[s1 * F + f];
        float a2 = st[s2 * F + f], a3 = st[s3 * F + f];
        acc += (a0 + a1) + (a2 + a3);
    }
    for (; j < end; ++j) acc += st[ecol[j] * F + f];
    float v = fmaf(dinv[d], acc, b[f]);
    out[idx] = RELU ? fmaxf(v, 0.0f) : v;
}

// ================= decode (float2 z loads) =================

__global__ void decode_kernel(const float* __restrict__ z, const int* __restrict__ pos,
                              const int* __restrict__ neg, float* __restrict__ logits, int EP) {
    int i = blockIdx.x * blockDim.x + threadIdx.x;
    if (i >= 2 * EP) return;
    int a, b;
    if (i < EP) { a = pos[i]; b = pos[EP + i]; }
    else        { int j = i - EP; a = neg[j]; b = neg[EP + j]; }
    const float2* za = (const float2*)(z + (size_t)a * H2_);
    const float2* zb = (const float2*)(z + (size_t)b * H2_);
    float acc = 0.0f;
#pragma unroll
    for (int f = 0; f < 5; ++f) {
        float2 va = za[f], vb = zb[f];
        acc = fmaf(va.x, vb.x, acc);
        acc = fmaf(va.y, vb.y, acc);
    }
    logits[i] = acc;
}

// ================= launch =================

extern "C" void kernel_launch(void* const* d_in, const int* in_sizes, int n_in,
                              void* d_out, int out_size, void* d_ws, size_t ws_size,
                              hipStream_t stream) {
    const float* x   = (const float*)d_in[0];
    const float* W1  = (const float*)d_in[1];
    const float* b1  = (const float*)d_in[2];
    const float* W2  = (const float*)d_in[3];
    const float* b2  = (const float*)d_in[4];
    const int* train = (const int*)d_in[5];
    const int* pos   = (const int*)d_in[6];
    const int* neg   = (const int*)d_in[7];

    const int N  = in_sizes[0] / FIN;       // 100000
    const int E  = in_sizes[5] / 2;         // 3200000
    const int EP = in_sizes[6] / 2;         // 1600000

    const int* tsrc = train;
    const int* tdst = train + E;

    // ---- workspace layout (~37 MB peak) ----
    // ints: rowptr[N+1] | bcnt[NB_MAX] | sbcnt[NSB_MAX] | bbase[NB_MAX+1] | bcursor[NB_MAX]
    // floats: dinv[N]
    // regA = 32N floats (12.8MB): pairbuf2 int[E=32N] -> st1p bf16[N*64] -> st2[10N]|out2[10N]
    // regB = 50N floats (20MB):   pairbuf1 int[49*SB_CAP=16.1MB] -> out1[50N]
    size_t off = 0;
    int* rowptr   = (int*)d_ws;              off += (size_t)N + 1;
    int* bcnt     = (int*)d_ws + off;        off += NB_MAX;
    int* sbcnt    = (int*)d_ws + off;        off += NSB_MAX;
    int* bbase    = (int*)d_ws + off;        off += NB_MAX + 1;
    int* bcursor  = (int*)d_ws + off;        off += NB_MAX;
    float* dinv   = (float*)d_ws + off;      off += N;
    off = (off + 3) & ~(size_t)3;            // 16B-align
    float* regA   = (float*)d_ws + off;      off += (size_t)32 * N;
    float* regB   = (float*)d_ws + off;
    int* pairbuf2 = (int*)regA;                      // E ints, dead after fill
    unsigned short* st1p = (unsigned short*)regA;    // 64N ushorts = 128N bytes
    float* st2    = regA;                            // overlays st1p after agg1
    float* out2   = regA + (size_t)10 * N;           // z
    int* pairbuf1 = (int*)regB;                      // 49*SB_CAP ints, dead after fine
    float* out1   = regB;                            // h after relu, 50N floats
    int* ecol     = (int*)d_out;                     // E ints; dead before decode
    float* logits = (float*)d_out;

    const int NB2 = (N + BKT_W - 1) >> BKT_SHIFT;   // 782 <= NB_MAX
    const int NSB = (N + SB_W - 1) >> SB_SHIFT;     // 49 <= NSB_MAX
    const int P1B = (E + P1_CHUNK - 1) / P1_CHUNK;  // 391
    const int P1FB = (SB_CAP + P1F_CHUNK - 1) / P1F_CHUNK;   // 20

    // ---- CSR build (fused count+partition, fixed-capacity SB segments) ----
    hipMemsetAsync(bcnt, 0, (NB_MAX + NSB_MAX) * sizeof(int), stream);  // bcnt + sbcnt
    partition_sb<<<P1B, 256, 0, stream>>>(tsrc, tdst, sbcnt, bcnt, pairbuf1, E, NSB);
    bucket_scan<<<1, 256, 0, stream>>>(bcnt, bbase, bcursor, NB2, E);
    partition_fine<<<dim3(P1FB, NSB), 256, 0, stream>>>(pairbuf1, sbcnt, bcursor, pairbuf2);
    bucket_fill_scan<<<NB2, 256, 0, stream>>>(pairbuf2, bbase, rowptr, dinv, ecol, N, E);

    // ---- layer 1 ----
    gemm1_kernel<<<(N + G1_NODES - 1) / G1_NODES, 256, 0, stream>>>(x, W1, dinv, st1p, N);
    csr_aggregate1<<<(N * F2 + 255) / 256, 256, 0, stream>>>(
        st1p, rowptr, ecol, dinv, b1, out1, N);

    // ---- layer 2 ----
    gemm2_kernel<<<(N * H2_ + 255) / 256, 256, 0, stream>>>(out1, W2, dinv, st2, N * H2_);
    csr_aggregate<H2_, false><<<(N * H2_ + 255) / 256, 256, 0, stream>>>(
        st2, rowptr, ecol, dinv, b2, out2, N);

    // ---- decode ----
    decode_kernel<<<(2 * EP + 255) / 256, 256, 0, stream>>>(out2, pos, neg, logits, EP);
}